// Round 1
// baseline (2551.011 us; speedup 1.0000x reference)
//
#include <hip/hip_runtime.h>

#define N_NODES 50000
#define N_EDGES 800000
#define HD 128
#define NLAYERS 5
#define EINC 16
#define NG 512

// ---------------- embedding: h[n][c] = emb[x[n]][c] ----------------
__global__ __launch_bounds__(256) void k_embed(const int* __restrict__ x,
                                               const float* __restrict__ emb,
                                               float* __restrict__ h) {
  int i = blockIdx.x * 256 + threadIdx.x;       // float4 index
  if (i < N_NODES * 32) {
    int n = i >> 5, cv = i & 31;
    *(float4*)&h[n * HD + cv * 4] = *(const float4*)&emb[x[n] * HD + cv * 4];
  }
}

// ------------- fused edge-MLP + gather + relu + scatter-add -------------
// one wave per edge; lane handles channels (lane, lane+64)
__global__ __launch_bounds__(256) void k_edge(const int* __restrict__ ei,
                                              const float* __restrict__ ea,
                                              const float* __restrict__ W,   // [16][128] layer slice
                                              const float* __restrict__ eb,  // [128]
                                              const float* __restrict__ h,
                                              float* __restrict__ agg) {
  __shared__ float sW[EINC * HD];
  __shared__ float sEb[HD];
  for (int t = threadIdx.x; t < EINC * HD; t += 256) sW[t] = W[t];
  if (threadIdx.x < HD) sEb[threadIdx.x] = eb[threadIdx.x];
  __syncthreads();
  const int wid = threadIdx.x >> 6;
  const int lane = threadIdx.x & 63;
  for (int e = blockIdx.x * 4 + wid; e < N_EDGES; e += gridDim.x * 4) {
    int src = ei[e];
    int dst = ei[N_EDGES + e];
    float eav = (lane < EINC) ? ea[e * EINC + lane] : 0.0f;
    float acc0 = sEb[lane], acc1 = sEb[lane + 64];
#pragma unroll
    for (int k = 0; k < EINC; ++k) {
      float a = __shfl(eav, k, 64);
      acc0 += a * sW[k * HD + lane];
      acc1 += a * sW[k * HD + lane + 64];
    }
    float m0 = fmaxf(h[src * HD + lane] + acc0, 0.0f);
    float m1 = fmaxf(h[src * HD + lane + 64] + acc1, 0.0f);
    unsafeAtomicAdd(&agg[dst * HD + lane], m0);
    unsafeAtomicAdd(&agg[dst * HD + lane + 64], m1);
  }
}

// ---------- GEMM1: y1 = ((1+eps)h + agg) @ W[128,256] + b ; col stats ----------
__global__ __launch_bounds__(256) void k_gemm1(const float* __restrict__ h,
                                               const float* __restrict__ agg,
                                               const float* __restrict__ W,
                                               const float* __restrict__ bias,
                                               const float* __restrict__ epsA, int layer,
                                               float* __restrict__ y1,
                                               float* __restrict__ gsum,
                                               float* __restrict__ gsq) {
  __shared__ float sm[32 * 68 + 32 * 256];
  float* sAT = sm;             // [k][row], stride 68
  float* sB = sm + 32 * 68;    // [k][c], stride 256
  const int tid = threadIdx.x;
  const int tx = tid & 15;
  const int ty = tid >> 4;
  const int n0 = blockIdx.x * 64;
  const float epsv = 1.0f + epsA[layer];
  float acc[4][16];
#pragma unroll
  for (int r = 0; r < 4; ++r)
#pragma unroll
    for (int c = 0; c < 16; ++c) acc[r][c] = 0.0f;

  for (int k0 = 0; k0 < 128; k0 += 32) {
#pragma unroll
    for (int f = tid; f < 512; f += 256) {   // A: 64 rows x 32 k, fused z
      int row = f >> 3, cv = f & 7;
      int n = n0 + row;
      float4 z = make_float4(0.f, 0.f, 0.f, 0.f);
      if (n < N_NODES) {
        float4 hv = *(const float4*)&h[n * HD + k0 + cv * 4];
        float4 av = *(const float4*)&agg[n * HD + k0 + cv * 4];
        z.x = epsv * hv.x + av.x; z.y = epsv * hv.y + av.y;
        z.z = epsv * hv.z + av.z; z.w = epsv * hv.w + av.w;
      }
      sAT[(cv * 4 + 0) * 68 + row] = z.x;
      sAT[(cv * 4 + 1) * 68 + row] = z.y;
      sAT[(cv * 4 + 2) * 68 + row] = z.z;
      sAT[(cv * 4 + 3) * 68 + row] = z.w;
    }
#pragma unroll
    for (int f = tid; f < 2048; f += 256) {  // B: 32 k x 256 c
      int row = f >> 6, cv = f & 63;
      *(float4*)&sB[row * 256 + cv * 4] = *(const float4*)&W[(k0 + row) * 256 + cv * 4];
    }
    __syncthreads();
#pragma unroll
    for (int kk = 0; kk < 32; ++kk) {
      float av[4];
      *(float4*)av = *(const float4*)&sAT[kk * 68 + ty * 4];
#pragma unroll
      for (int g2 = 0; g2 < 4; ++g2) {
        float bv[4];
        *(float4*)bv = *(const float4*)&sB[kk * 256 + g2 * 64 + tx * 4];
#pragma unroll
        for (int r = 0; r < 4; ++r)
#pragma unroll
          for (int j = 0; j < 4; ++j) acc[r][g2 * 4 + j] += av[r] * bv[j];
      }
    }
    __syncthreads();
  }
  // epilogue: bias, store, stats
  float bs[16];
#pragma unroll
  for (int g2 = 0; g2 < 4; ++g2) *(float4*)&bs[g2 * 4] = *(const float4*)&bias[g2 * 64 + tx * 4];
  float s[16], q[16];
#pragma unroll
  for (int c = 0; c < 16; ++c) { s[c] = 0.f; q[c] = 0.f; }
#pragma unroll
  for (int r = 0; r < 4; ++r) {
    int n = n0 + ty * 4 + r;
    if (n < N_NODES) {
#pragma unroll
      for (int g2 = 0; g2 < 4; ++g2) {
        float v[4];
#pragma unroll
        for (int j = 0; j < 4; ++j) {
          v[j] = acc[r][g2 * 4 + j] + bs[g2 * 4 + j];
          s[g2 * 4 + j] += v[j];
          q[g2 * 4 + j] += v[j] * v[j];
        }
        *(float4*)&y1[(long long)n * 256 + g2 * 64 + tx * 4] = *(float4*)v;
      }
    }
  }
  __syncthreads();  // smem reuse
#pragma unroll
  for (int g2 = 0; g2 < 4; ++g2) {
    *(float4*)&sm[ty * 256 + g2 * 64 + tx * 4] = *(float4*)&s[g2 * 4];
    *(float4*)&sm[4096 + ty * 256 + g2 * 64 + tx * 4] = *(float4*)&q[g2 * 4];
  }
  __syncthreads();
  {
    int c = tid;   // 256 cols
    float sv = 0.f, qv = 0.f;
#pragma unroll
    for (int t = 0; t < 16; ++t) { sv += sm[t * 256 + c]; qv += sm[4096 + t * 256 + c]; }
    unsafeAtomicAdd(&gsum[c], sv);
    unsafeAtomicAdd(&gsq[c], qv);
  }
}

// ---------- GEMM2: y2 = relu(y1*sc+sh) @ W[256,128] + b ; col stats ----------
__global__ __launch_bounds__(256) void k_gemm2(const float* __restrict__ y1,
                                               const float* __restrict__ sc,
                                               const float* __restrict__ sh,
                                               const float* __restrict__ W,
                                               const float* __restrict__ bias,
                                               float* __restrict__ y2,
                                               float* __restrict__ gsum,
                                               float* __restrict__ gsq) {
  __shared__ float sm[32 * 68 + 32 * 128];
  float* sAT = sm;
  float* sB = sm + 32 * 68;
  const int tid = threadIdx.x;
  const int tx = tid & 15;
  const int ty = tid >> 4;
  const int n0 = blockIdx.x * 64;
  float acc[4][8];
#pragma unroll
  for (int r = 0; r < 4; ++r)
#pragma unroll
    for (int c = 0; c < 8; ++c) acc[r][c] = 0.0f;

  for (int k0 = 0; k0 < 256; k0 += 32) {
#pragma unroll
    for (int f = tid; f < 512; f += 256) {
      int row = f >> 3, cv = f & 7;
      int n = n0 + row;
      float4 z = make_float4(0.f, 0.f, 0.f, 0.f);
      if (n < N_NODES) {
        float4 yv = *(const float4*)&y1[(long long)n * 256 + k0 + cv * 4];
        float4 scv = *(const float4*)&sc[k0 + cv * 4];
        float4 shv = *(const float4*)&sh[k0 + cv * 4];
        z.x = fmaxf(yv.x * scv.x + shv.x, 0.f);
        z.y = fmaxf(yv.y * scv.y + shv.y, 0.f);
        z.z = fmaxf(yv.z * scv.z + shv.z, 0.f);
        z.w = fmaxf(yv.w * scv.w + shv.w, 0.f);
      }
      sAT[(cv * 4 + 0) * 68 + row] = z.x;
      sAT[(cv * 4 + 1) * 68 + row] = z.y;
      sAT[(cv * 4 + 2) * 68 + row] = z.z;
      sAT[(cv * 4 + 3) * 68 + row] = z.w;
    }
#pragma unroll
    for (int f = tid; f < 1024; f += 256) {
      int row = f >> 5, cv = f & 31;
      *(float4*)&sB[row * 128 + cv * 4] = *(const float4*)&W[(k0 + row) * 128 + cv * 4];
    }
    __syncthreads();
#pragma unroll
    for (int kk = 0; kk < 32; ++kk) {
      float av[4];
      *(float4*)av = *(const float4*)&sAT[kk * 68 + ty * 4];
#pragma unroll
      for (int g2 = 0; g2 < 2; ++g2) {
        float bv[4];
        *(float4*)bv = *(const float4*)&sB[kk * 128 + g2 * 64 + tx * 4];
#pragma unroll
        for (int r = 0; r < 4; ++r)
#pragma unroll
          for (int j = 0; j < 4; ++j) acc[r][g2 * 4 + j] += av[r] * bv[j];
      }
    }
    __syncthreads();
  }
  float bs[8];
#pragma unroll
  for (int g2 = 0; g2 < 2; ++g2) *(float4*)&bs[g2 * 4] = *(const float4*)&bias[g2 * 64 + tx * 4];
  float s[8], q[8];
#pragma unroll
  for (int c = 0; c < 8; ++c) { s[c] = 0.f; q[c] = 0.f; }
#pragma unroll
  for (int r = 0; r < 4; ++r) {
    int n = n0 + ty * 4 + r;
    if (n < N_NODES) {
#pragma unroll
      for (int g2 = 0; g2 < 2; ++g2) {
        float v[4];
#pragma unroll
        for (int j = 0; j < 4; ++j) {
          v[j] = acc[r][g2 * 4 + j] + bs[g2 * 4 + j];
          s[g2 * 4 + j] += v[j];
          q[g2 * 4 + j] += v[j] * v[j];
        }
        *(float4*)&y2[(long long)n * HD + g2 * 64 + tx * 4] = *(float4*)v;
      }
    }
  }
  __syncthreads();
#pragma unroll
  for (int g2 = 0; g2 < 2; ++g2) {
    *(float4*)&sm[ty * 128 + g2 * 64 + tx * 4] = *(float4*)&s[g2 * 4];
    *(float4*)&sm[2048 + ty * 128 + g2 * 64 + tx * 4] = *(float4*)&q[g2 * 4];
  }
  __syncthreads();
  if (tid < 128) {
    int c = tid;
    float sv = 0.f, qv = 0.f;
#pragma unroll
    for (int t = 0; t < 16; ++t) { sv += sm[t * 128 + c]; qv += sm[2048 + t * 128 + c]; }
    unsafeAtomicAdd(&gsum[c], sv);
    unsafeAtomicAdd(&gsq[c], qv);
  }
}

// ---------------- BN finalize: stats -> scale/shift ----------------
__global__ void k_bnfin(const float* __restrict__ sum, const float* __restrict__ sq,
                        const float* __restrict__ g, const float* __restrict__ b,
                        float* __restrict__ sc, float* __restrict__ sh, int C) {
  int c = blockIdx.x * blockDim.x + threadIdx.x;
  if (c < C) {
    const float invN = 1.0f / (float)N_NODES;
    float m = sum[c] * invN;
    float v = fmaxf(sq[c] * invN - m * m, 0.0f);
    float rs = rsqrtf(v + 1e-5f);
    float scale = g[c] * rs;
    sc[c] = scale;
    sh[c] = b[c] - m * scale;
  }
}

// ---------------- apply BN (+optional relu) to produce next h ----------------
__global__ __launch_bounds__(256) void k_bnapply(const float* __restrict__ y2,
                                                 const float* __restrict__ sc,
                                                 const float* __restrict__ sh,
                                                 float* __restrict__ h, int dorelu) {
  int i = blockIdx.x * 256 + threadIdx.x;
  if (i < N_NODES * 32) {
    int cv = i & 31;
    float4 v = *(const float4*)&y2[i * 4];
    float4 s4 = *(const float4*)&sc[cv * 4];
    float4 h4 = *(const float4*)&sh[cv * 4];
    float4 o;
    o.x = v.x * s4.x + h4.x; o.y = v.y * s4.y + h4.y;
    o.z = v.z * s4.z + h4.z; o.w = v.w * s4.w + h4.w;
    if (dorelu) {
      o.x = fmaxf(o.x, 0.f); o.y = fmaxf(o.y, 0.f);
      o.z = fmaxf(o.z, 0.f); o.w = fmaxf(o.w, 0.f);
    }
    *(float4*)&h[i * 4] = o;
  }
}

// ---------------- pooling: atomics into per-graph sums + counts ----------------
__global__ __launch_bounds__(256) void k_pool(const float* __restrict__ h,
                                              const int* __restrict__ batch,
                                              float* __restrict__ sums,
                                              float* __restrict__ cnt) {
  int i = blockIdx.x * 256 + threadIdx.x;
  if (i < N_NODES * 32) {
    int n = i >> 5, cv = i & 31;
    int b = batch[n];
    float4 v = *(const float4*)&h[i * 4];
    unsafeAtomicAdd(&sums[b * HD + cv * 4 + 0], v.x);
    unsafeAtomicAdd(&sums[b * HD + cv * 4 + 1], v.y);
    unsafeAtomicAdd(&sums[b * HD + cv * 4 + 2], v.z);
    unsafeAtomicAdd(&sums[b * HD + cv * 4 + 3], v.w);
    if (cv == 0) unsafeAtomicAdd(&cnt[b], 1.0f);
  }
}

// ---------------- final: out = (sums/max(cnt,1)) @ out_W + out_b ----------------
__global__ __launch_bounds__(128) void k_final(const float* __restrict__ sums,
                                               const float* __restrict__ cnt,
                                               const float* __restrict__ oW,
                                               const float* __restrict__ ob,
                                               float* __restrict__ out) {
  __shared__ float sP[HD];
  int g = blockIdx.x;
  int c = threadIdx.x;
  float cg = fmaxf(cnt[g], 1.0f);
  sP[c] = sums[g * HD + c] / cg;
  __syncthreads();
  float acc = ob[c];
#pragma unroll 8
  for (int k = 0; k < HD; ++k) acc += sP[k] * oW[k * HD + c];
  out[g * HD + c] = acc;
}

extern "C" void kernel_launch(void* const* d_in, const int* in_sizes, int n_in,
                              void* d_out, int out_size, void* d_ws, size_t ws_size,
                              hipStream_t stream) {
  const int* x = (const int*)d_in[0];
  const int* ei = (const int*)d_in[1];
  const float* ea = (const float*)d_in[2];
  const int* batch = (const int*)d_in[3];
  const float* emb = (const float*)d_in[4];
  const float* eW = (const float*)d_in[5];
  const float* eb = (const float*)d_in[6];
  const float* epsA = (const float*)d_in[7];
  const float* W1 = (const float*)d_in[8];
  const float* b1 = (const float*)d_in[9];
  const float* g1 = (const float*)d_in[10];
  const float* be1 = (const float*)d_in[11];
  const float* W2 = (const float*)d_in[12];
  const float* b2 = (const float*)d_in[13];
  const float* bng = (const float*)d_in[14];
  const float* bnb = (const float*)d_in[15];
  const float* oW = (const float*)d_in[16];
  const float* ob = (const float*)d_in[17];
  float* out = (float*)d_out;

  float* ws = (float*)d_ws;
  float* h   = ws;                       // 6,400,000
  float* agg = h + 6400000;              // 6,400,000 (y2 aliases agg)
  float* y1  = agg + 6400000;            // 12,800,000
  float* y2  = agg;                      // alias: agg dead after gemm1
  float* stats = y1 + 12800000;          // 768 (sum1 256 | sq1 256 | sum2 128 | sq2 128)
  float* sc1 = stats + 768;              // 256
  float* sh1 = sc1 + 256;                // 256
  float* sc2 = sh1 + 256;                // 128
  float* sh2 = sc2 + 128;                // 128
  float* psum = sh2 + 128;               // 65536
  float* pcnt = psum + 65536;            // 512

  const int vec_blocks = (N_NODES * 32 + 255) / 256;
  k_embed<<<vec_blocks, 256, 0, stream>>>(x, emb, h);

  for (int l = 0; l < NLAYERS; ++l) {
    hipMemsetAsync(agg, 0, (size_t)6400000 * 4, stream);
    hipMemsetAsync(stats, 0, 768 * 4, stream);
    k_edge<<<4096, 256, 0, stream>>>(ei, ea, eW + (size_t)l * EINC * HD, eb + l * HD, h, agg);
    k_gemm1<<<(N_NODES + 63) / 64, 256, 0, stream>>>(h, agg, W1 + (size_t)l * 128 * 256,
                                                     b1 + l * 256, epsA, l, y1, stats, stats + 256);
    k_bnfin<<<1, 256, 0, stream>>>(stats, stats + 256, g1 + l * 256, be1 + l * 256, sc1, sh1, 256);
    k_gemm2<<<(N_NODES + 63) / 64, 256, 0, stream>>>(y1, sc1, sh1, W2 + (size_t)l * 256 * 128,
                                                     b2 + l * HD, y2, stats + 512, stats + 640);
    k_bnfin<<<1, 128, 0, stream>>>(stats + 512, stats + 640, bng + l * HD, bnb + l * HD, sc2, sh2, 128);
    k_bnapply<<<vec_blocks, 256, 0, stream>>>(y2, sc2, sh2, h, (l < NLAYERS - 1) ? 1 : 0);
  }

  hipMemsetAsync(psum, 0, (65536 + 512) * 4, stream);
  k_pool<<<vec_blocks, 256, 0, stream>>>(h, batch, psum, pcnt);
  k_final<<<NG, 128, 0, stream>>>(psum, pcnt, oW, ob, out);
}

// Round 2
// 1845.298 us; speedup vs baseline: 1.3824x; 1.3824x over previous
//
#include <hip/hip_runtime.h>

#define N_NODES 50000
#define N_EDGES 800000
#define HD 128
#define NLAYERS 5
#define EINC 16
#define NG 512

// ---------------- embedding: h[n][c] = emb[x[n]][c] ----------------
__global__ __launch_bounds__(256) void k_embed(const int* __restrict__ x,
                                               const float* __restrict__ emb,
                                               float* __restrict__ h) {
  int i = blockIdx.x * 256 + threadIdx.x;       // float4 index
  if (i < N_NODES * 32) {
    int n = i >> 5, cv = i & 31;
    *(float4*)&h[n * HD + cv * 4] = *(const float4*)&emb[x[n] * HD + cv * 4];
  }
}

// ---------------- CSR build ----------------
__global__ __launch_bounds__(256) void k_hist(const int* __restrict__ ei,
                                              int* __restrict__ deg) {
  int e = blockIdx.x * 256 + threadIdx.x;
  if (e < N_EDGES) atomicAdd(&deg[ei[N_EDGES + e]], 1);
}

__global__ __launch_bounds__(256) void k_scan1(const int* __restrict__ deg,
                                               int* __restrict__ incl,
                                               int* __restrict__ bsum) {
  __shared__ int s[256];
  int i = blockIdx.x * 256 + threadIdx.x;
  int v = (i < N_NODES) ? deg[i] : 0;
  s[threadIdx.x] = v;
  __syncthreads();
  for (int d = 1; d < 256; d <<= 1) {
    int t = (threadIdx.x >= d) ? s[threadIdx.x - d] : 0;
    __syncthreads();
    s[threadIdx.x] += t;
    __syncthreads();
  }
  if (i < N_NODES) incl[i] = s[threadIdx.x];
  if (threadIdx.x == 255) bsum[blockIdx.x] = s[255];
}

__global__ void k_scan2(int* __restrict__ bsum, int nb) {
  __shared__ int s[256];
  int v = (threadIdx.x < nb) ? bsum[threadIdx.x] : 0;
  s[threadIdx.x] = v;
  __syncthreads();
  for (int d = 1; d < 256; d <<= 1) {
    int t = (threadIdx.x >= d) ? s[threadIdx.x - d] : 0;
    __syncthreads();
    s[threadIdx.x] += t;
    __syncthreads();
  }
  if (threadIdx.x < nb) bsum[threadIdx.x] = s[threadIdx.x];
}

__global__ __launch_bounds__(256) void k_scan3(const int* __restrict__ deg,
                                               const int* __restrict__ incl,
                                               const int* __restrict__ bsum,
                                               int* __restrict__ offs,
                                               int* __restrict__ cursor) {
  int i = blockIdx.x * 256 + threadIdx.x;
  if (i < N_NODES) {
    int base = (blockIdx.x > 0) ? bsum[blockIdx.x - 1] : 0;
    int start = base + incl[i] - deg[i];
    offs[i] = start;
    cursor[i] = start;
    if (i == N_NODES - 1) offs[N_NODES] = N_EDGES;
  }
}

__global__ __launch_bounds__(256) void k_scatter(const int* __restrict__ ei,
                                                 const float* __restrict__ ea,
                                                 int* __restrict__ cursor,
                                                 int* __restrict__ srcs,
                                                 int* __restrict__ eids,
                                                 float* __restrict__ ea_s,
                                                 int permuted) {
  int e = blockIdx.x * 256 + threadIdx.x;
  if (e < N_EDGES) {
    int dst = ei[N_EDGES + e];
    int pos = atomicAdd(&cursor[dst], 1);
    srcs[pos] = ei[e];
    eids[pos] = e;
    if (permuted) {
      float4 a0 = *(const float4*)&ea[(size_t)e * EINC];
      float4 a1 = *(const float4*)&ea[(size_t)e * EINC + 4];
      float4 a2 = *(const float4*)&ea[(size_t)e * EINC + 8];
      float4 a3 = *(const float4*)&ea[(size_t)e * EINC + 12];
      *(float4*)&ea_s[(size_t)pos * EINC] = a0;
      *(float4*)&ea_s[(size_t)pos * EINC + 4] = a1;
      *(float4*)&ea_s[(size_t)pos * EINC + 8] = a2;
      *(float4*)&ea_s[(size_t)pos * EINC + 12] = a3;
    }
  }
}

// -------- fused per-node aggregation: z = (1+eps)h + sum_in relu(h[src]+e) --------
// one wave per node; lane covers channels (lane, lane+64)
__global__ __launch_bounds__(256) void k_aggr(const int* __restrict__ offs,
                                              const int* __restrict__ srcs,
                                              const int* __restrict__ eids,
                                              const float* __restrict__ ea,
                                              const float* __restrict__ ea_s,
                                              const float* __restrict__ W,   // [16][128]
                                              const float* __restrict__ eb,  // [128]
                                              const float* __restrict__ epsA, int layer,
                                              const float* __restrict__ h,
                                              float* __restrict__ z,
                                              int permuted) {
  __shared__ float sW[EINC * HD];
  __shared__ float sEb[HD];
  for (int t = threadIdx.x; t < EINC * HD; t += 256) sW[t] = W[t];
  if (threadIdx.x < HD) sEb[threadIdx.x] = eb[threadIdx.x];
  __syncthreads();
  const int wid = threadIdx.x >> 6;
  const int lane = threadIdx.x & 63;
  int n = blockIdx.x * 4 + wid;
  if (n >= N_NODES) return;
  const float epsv = 1.0f + epsA[layer];
  int j0 = offs[n], j1 = offs[n + 1];
  float acc0 = epsv * h[n * HD + lane];
  float acc1 = epsv * h[n * HD + 64 + lane];
  for (int j = j0; j < j1; ++j) {
    int src = srcs[j];
    const float* earow = permuted ? &ea_s[(size_t)j * EINC] : &ea[(size_t)eids[j] * EINC];
    float eav = (lane < EINC) ? earow[lane] : 0.0f;
    float e0 = sEb[lane], e1 = sEb[lane + 64];
#pragma unroll
    for (int k = 0; k < EINC; ++k) {
      float a = __shfl(eav, k, 64);
      e0 += a * sW[k * HD + lane];
      e1 += a * sW[k * HD + lane + 64];
    }
    acc0 += fmaxf(h[src * HD + lane] + e0, 0.0f);
    acc1 += fmaxf(h[src * HD + 64 + lane] + e1, 0.0f);
  }
  z[n * HD + lane] = acc0;
  z[n * HD + 64 + lane] = acc1;
}

// ---------- GEMM1: y1 = z @ W[128,256] + b ; col stats ----------
__global__ __launch_bounds__(256) void k_gemm1(const float* __restrict__ z,
                                               const float* __restrict__ W,
                                               const float* __restrict__ bias,
                                               float* __restrict__ y1,
                                               float* __restrict__ gsum,
                                               float* __restrict__ gsq) {
  __shared__ float sm[32 * 68 + 32 * 256];
  float* sAT = sm;             // [k][row], stride 68
  float* sB = sm + 32 * 68;    // [k][c], stride 256
  const int tid = threadIdx.x;
  const int tx = tid & 15;
  const int ty = tid >> 4;
  const int n0 = blockIdx.x * 64;
  float acc[4][16];
#pragma unroll
  for (int r = 0; r < 4; ++r)
#pragma unroll
    for (int c = 0; c < 16; ++c) acc[r][c] = 0.0f;

  for (int k0 = 0; k0 < 128; k0 += 32) {
#pragma unroll
    for (int f = tid; f < 512; f += 256) {   // A: 64 rows x 32 k
      int row = f >> 3, cv = f & 7;
      int n = n0 + row;
      float4 zv = make_float4(0.f, 0.f, 0.f, 0.f);
      if (n < N_NODES) zv = *(const float4*)&z[n * HD + k0 + cv * 4];
      sAT[(cv * 4 + 0) * 68 + row] = zv.x;
      sAT[(cv * 4 + 1) * 68 + row] = zv.y;
      sAT[(cv * 4 + 2) * 68 + row] = zv.z;
      sAT[(cv * 4 + 3) * 68 + row] = zv.w;
    }
#pragma unroll
    for (int f = tid; f < 2048; f += 256) {  // B: 32 k x 256 c
      int row = f >> 6, cv = f & 63;
      *(float4*)&sB[row * 256 + cv * 4] = *(const float4*)&W[(k0 + row) * 256 + cv * 4];
    }
    __syncthreads();
#pragma unroll
    for (int kk = 0; kk < 32; ++kk) {
      float av[4];
      *(float4*)av = *(const float4*)&sAT[kk * 68 + ty * 4];
#pragma unroll
      for (int g2 = 0; g2 < 4; ++g2) {
        float bv[4];
        *(float4*)bv = *(const float4*)&sB[kk * 256 + g2 * 64 + tx * 4];
#pragma unroll
        for (int r = 0; r < 4; ++r)
#pragma unroll
          for (int j = 0; j < 4; ++j) acc[r][g2 * 4 + j] += av[r] * bv[j];
      }
    }
    __syncthreads();
  }
  float bs[16];
#pragma unroll
  for (int g2 = 0; g2 < 4; ++g2) *(float4*)&bs[g2 * 4] = *(const float4*)&bias[g2 * 64 + tx * 4];
  float s[16], q[16];
#pragma unroll
  for (int c = 0; c < 16; ++c) { s[c] = 0.f; q[c] = 0.f; }
#pragma unroll
  for (int r = 0; r < 4; ++r) {
    int n = n0 + ty * 4 + r;
    if (n < N_NODES) {
#pragma unroll
      for (int g2 = 0; g2 < 4; ++g2) {
        float v[4];
#pragma unroll
        for (int j = 0; j < 4; ++j) {
          v[j] = acc[r][g2 * 4 + j] + bs[g2 * 4 + j];
          s[g2 * 4 + j] += v[j];
          q[g2 * 4 + j] += v[j] * v[j];
        }
        *(float4*)&y1[(long long)n * 256 + g2 * 64 + tx * 4] = *(float4*)v;
      }
    }
  }
  __syncthreads();  // smem reuse
#pragma unroll
  for (int g2 = 0; g2 < 4; ++g2) {
    *(float4*)&sm[ty * 256 + g2 * 64 + tx * 4] = *(float4*)&s[g2 * 4];
    *(float4*)&sm[4096 + ty * 256 + g2 * 64 + tx * 4] = *(float4*)&q[g2 * 4];
  }
  __syncthreads();
  {
    int c = tid;
    float sv = 0.f, qv = 0.f;
#pragma unroll
    for (int t = 0; t < 16; ++t) { sv += sm[t * 256 + c]; qv += sm[4096 + t * 256 + c]; }
    unsafeAtomicAdd(&gsum[c], sv);
    unsafeAtomicAdd(&gsq[c], qv);
  }
}

// ---------- GEMM2: y2 = relu(y1*sc+sh) @ W[256,128] + b ; col stats ----------
__global__ __launch_bounds__(256) void k_gemm2(const float* __restrict__ y1,
                                               const float* __restrict__ sc,
                                               const float* __restrict__ sh,
                                               const float* __restrict__ W,
                                               const float* __restrict__ bias,
                                               float* __restrict__ y2,
                                               float* __restrict__ gsum,
                                               float* __restrict__ gsq) {
  __shared__ float sm[32 * 68 + 32 * 128];
  float* sAT = sm;
  float* sB = sm + 32 * 68;
  const int tid = threadIdx.x;
  const int tx = tid & 15;
  const int ty = tid >> 4;
  const int n0 = blockIdx.x * 64;
  float acc[4][8];
#pragma unroll
  for (int r = 0; r < 4; ++r)
#pragma unroll
    for (int c = 0; c < 8; ++c) acc[r][c] = 0.0f;

  for (int k0 = 0; k0 < 256; k0 += 32) {
#pragma unroll
    for (int f = tid; f < 512; f += 256) {
      int row = f >> 3, cv = f & 7;
      int n = n0 + row;
      float4 zv = make_float4(0.f, 0.f, 0.f, 0.f);
      if (n < N_NODES) {
        float4 yv = *(const float4*)&y1[(long long)n * 256 + k0 + cv * 4];
        float4 scv = *(const float4*)&sc[k0 + cv * 4];
        float4 shv = *(const float4*)&sh[k0 + cv * 4];
        zv.x = fmaxf(yv.x * scv.x + shv.x, 0.f);
        zv.y = fmaxf(yv.y * scv.y + shv.y, 0.f);
        zv.z = fmaxf(yv.z * scv.z + shv.z, 0.f);
        zv.w = fmaxf(yv.w * scv.w + shv.w, 0.f);
      }
      sAT[(cv * 4 + 0) * 68 + row] = zv.x;
      sAT[(cv * 4 + 1) * 68 + row] = zv.y;
      sAT[(cv * 4 + 2) * 68 + row] = zv.z;
      sAT[(cv * 4 + 3) * 68 + row] = zv.w;
    }
#pragma unroll
    for (int f = tid; f < 1024; f += 256) {
      int row = f >> 5, cv = f & 31;
      *(float4*)&sB[row * 128 + cv * 4] = *(const float4*)&W[(k0 + row) * 128 + cv * 4];
    }
    __syncthreads();
#pragma unroll
    for (int kk = 0; kk < 32; ++kk) {
      float av[4];
      *(float4*)av = *(const float4*)&sAT[kk * 68 + ty * 4];
#pragma unroll
      for (int g2 = 0; g2 < 2; ++g2) {
        float bv[4];
        *(float4*)bv = *(const float4*)&sB[kk * 128 + g2 * 64 + tx * 4];
#pragma unroll
        for (int r = 0; r < 4; ++r)
#pragma unroll
          for (int j = 0; j < 4; ++j) acc[r][g2 * 4 + j] += av[r] * bv[j];
      }
    }
    __syncthreads();
  }
  float bs[8];
#pragma unroll
  for (int g2 = 0; g2 < 2; ++g2) *(float4*)&bs[g2 * 4] = *(const float4*)&bias[g2 * 64 + tx * 4];
  float s[8], q[8];
#pragma unroll
  for (int c = 0; c < 8; ++c) { s[c] = 0.f; q[c] = 0.f; }
#pragma unroll
  for (int r = 0; r < 4; ++r) {
    int n = n0 + ty * 4 + r;
    if (n < N_NODES) {
#pragma unroll
      for (int g2 = 0; g2 < 2; ++g2) {
        float v[4];
#pragma unroll
        for (int j = 0; j < 4; ++j) {
          v[j] = acc[r][g2 * 4 + j] + bs[g2 * 4 + j];
          s[g2 * 4 + j] += v[j];
          q[g2 * 4 + j] += v[j] * v[j];
        }
        *(float4*)&y2[(long long)n * HD + g2 * 64 + tx * 4] = *(float4*)v;
      }
    }
  }
  __syncthreads();
#pragma unroll
  for (int g2 = 0; g2 < 2; ++g2) {
    *(float4*)&sm[ty * 128 + g2 * 64 + tx * 4] = *(float4*)&s[g2 * 4];
    *(float4*)&sm[2048 + ty * 128 + g2 * 64 + tx * 4] = *(float4*)&q[g2 * 4];
  }
  __syncthreads();
  if (tid < 128) {
    int c = tid;
    float sv = 0.f, qv = 0.f;
#pragma unroll
    for (int t = 0; t < 16; ++t) { sv += sm[t * 128 + c]; qv += sm[2048 + t * 128 + c]; }
    unsafeAtomicAdd(&gsum[c], sv);
    unsafeAtomicAdd(&gsq[c], qv);
  }
}

// ---------------- BN finalize: stats -> scale/shift ----------------
__global__ void k_bnfin(const float* __restrict__ sum, const float* __restrict__ sq,
                        const float* __restrict__ g, const float* __restrict__ b,
                        float* __restrict__ sc, float* __restrict__ sh, int C) {
  int c = blockIdx.x * blockDim.x + threadIdx.x;
  if (c < C) {
    const float invN = 1.0f / (float)N_NODES;
    float m = sum[c] * invN;
    float v = fmaxf(sq[c] * invN - m * m, 0.0f);
    float rs = rsqrtf(v + 1e-5f);
    float scale = g[c] * rs;
    sc[c] = scale;
    sh[c] = b[c] - m * scale;
  }
}

// ---------------- apply BN (+optional relu) ----------------
__global__ __launch_bounds__(256) void k_bnapply(const float* __restrict__ y2,
                                                 const float* __restrict__ sc,
                                                 const float* __restrict__ sh,
                                                 float* __restrict__ h, int dorelu) {
  int i = blockIdx.x * 256 + threadIdx.x;
  if (i < N_NODES * 32) {
    int cv = i & 31;
    float4 v = *(const float4*)&y2[i * 4];
    float4 s4 = *(const float4*)&sc[cv * 4];
    float4 h4 = *(const float4*)&sh[cv * 4];
    float4 o;
    o.x = v.x * s4.x + h4.x; o.y = v.y * s4.y + h4.y;
    o.z = v.z * s4.z + h4.z; o.w = v.w * s4.w + h4.w;
    if (dorelu) {
      o.x = fmaxf(o.x, 0.f); o.y = fmaxf(o.y, 0.f);
      o.z = fmaxf(o.z, 0.f); o.w = fmaxf(o.w, 0.f);
    }
    *(float4*)&h[i * 4] = o;
  }
}

// ---------------- pooling ----------------
__global__ __launch_bounds__(256) void k_pool(const float* __restrict__ h,
                                              const int* __restrict__ batch,
                                              float* __restrict__ sums,
                                              float* __restrict__ cnt) {
  int i = blockIdx.x * 256 + threadIdx.x;
  if (i < N_NODES * 32) {
    int n = i >> 5, cv = i & 31;
    int b = batch[n];
    float4 v = *(const float4*)&h[i * 4];
    unsafeAtomicAdd(&sums[b * HD + cv * 4 + 0], v.x);
    unsafeAtomicAdd(&sums[b * HD + cv * 4 + 1], v.y);
    unsafeAtomicAdd(&sums[b * HD + cv * 4 + 2], v.z);
    unsafeAtomicAdd(&sums[b * HD + cv * 4 + 3], v.w);
    if (cv == 0) unsafeAtomicAdd(&cnt[b], 1.0f);
  }
}

// ---------------- final GEMM ----------------
__global__ __launch_bounds__(128) void k_final(const float* __restrict__ sums,
                                               const float* __restrict__ cnt,
                                               const float* __restrict__ oW,
                                               const float* __restrict__ ob,
                                               float* __restrict__ out) {
  __shared__ float sP[HD];
  int g = blockIdx.x;
  int c = threadIdx.x;
  float cg = fmaxf(cnt[g], 1.0f);
  sP[c] = sums[g * HD + c] / cg;
  __syncthreads();
  float acc = ob[c];
#pragma unroll 8
  for (int k = 0; k < HD; ++k) acc += sP[k] * oW[k * HD + c];
  out[g * HD + c] = acc;
}

extern "C" void kernel_launch(void* const* d_in, const int* in_sizes, int n_in,
                              void* d_out, int out_size, void* d_ws, size_t ws_size,
                              hipStream_t stream) {
  const int* x = (const int*)d_in[0];
  const int* ei = (const int*)d_in[1];
  const float* ea = (const float*)d_in[2];
  const int* batch = (const int*)d_in[3];
  const float* emb = (const float*)d_in[4];
  const float* eW = (const float*)d_in[5];
  const float* eb = (const float*)d_in[6];
  const float* epsA = (const float*)d_in[7];
  const float* W1 = (const float*)d_in[8];
  const float* b1 = (const float*)d_in[9];
  const float* g1 = (const float*)d_in[10];
  const float* be1 = (const float*)d_in[11];
  const float* W2 = (const float*)d_in[12];
  const float* b2 = (const float*)d_in[13];
  const float* bng = (const float*)d_in[14];
  const float* bnb = (const float*)d_in[15];
  const float* oW = (const float*)d_in[16];
  const float* ob = (const float*)d_in[17];
  float* out = (float*)d_out;

  // ----- workspace layout: ints first, then floats -----
  int* ip = (int*)d_ws;
  int* deg = ip;                         // 50,000
  int* incl = deg + 50000;               // 50,000
  int* offs = incl + 50000;              // 50,001
  int* cursor = offs + 50001;            // 50,000
  int* srcs = cursor + 50000;            // 800,000
  int* eids = srcs + 800000;             // 800,000
  int* bsum = eids + 800000;             // 196 (pad to 1,800,200 total ints)
  float* fp = (float*)(ip + 1800200);
  float* h = fp;                         // 6,400,000
  float* zbuf = h + 6400000;             // 6,400,000 (z and y2 alias)
  float* y1 = zbuf + 6400000;            // 12,800,000
  float* stats = y1 + 12800000;          // 768
  float* sc1 = stats + 768;              // 256
  float* sh1 = sc1 + 256;                // 256
  float* sc2 = sh1 + 256;                // 128
  float* sh2 = sc2 + 128;                // 128
  float* psum = sh2 + 128;               // 65,536
  float* pcnt = psum + 65536;            // 512
  float* ea_s = pcnt + 512;              // 12,800,000 (optional)

  size_t needed_with = (size_t)(ea_s + 12800000 - (float*)d_ws) * 4;
  int permuted = (ws_size >= needed_with) ? 1 : 0;

  const int vec_blocks = (N_NODES * 32 + 255) / 256;
  const int edge_blocks = (N_EDGES + 255) / 256;
  const int node_blocks = (N_NODES + 255) / 256;

  k_embed<<<vec_blocks, 256, 0, stream>>>(x, emb, h);

  // CSR build (once per launch)
  hipMemsetAsync(deg, 0, 50000 * sizeof(int), stream);
  k_hist<<<edge_blocks, 256, 0, stream>>>(ei, deg);
  k_scan1<<<node_blocks, 256, 0, stream>>>(deg, incl, bsum);
  k_scan2<<<1, 256, 0, stream>>>(bsum, node_blocks);
  k_scan3<<<node_blocks, 256, 0, stream>>>(deg, incl, bsum, offs, cursor);
  k_scatter<<<edge_blocks, 256, 0, stream>>>(ei, ea, cursor, srcs, eids, ea_s, permuted);

  for (int l = 0; l < NLAYERS; ++l) {
    hipMemsetAsync(stats, 0, 768 * sizeof(float), stream);
    k_aggr<<<(N_NODES + 3) / 4, 256, 0, stream>>>(offs, srcs, eids, ea, ea_s,
                                                  eW + (size_t)l * EINC * HD, eb + l * HD,
                                                  epsA, l, h, zbuf, permuted);
    k_gemm1<<<(N_NODES + 63) / 64, 256, 0, stream>>>(zbuf, W1 + (size_t)l * 128 * 256,
                                                     b1 + l * 256, y1, stats, stats + 256);
    k_bnfin<<<1, 256, 0, stream>>>(stats, stats + 256, g1 + l * 256, be1 + l * 256, sc1, sh1, 256);
    k_gemm2<<<(N_NODES + 63) / 64, 256, 0, stream>>>(y1, sc1, sh1, W2 + (size_t)l * 256 * 128,
                                                     b2 + l * HD, zbuf, stats + 512, stats + 640);
    k_bnfin<<<1, 128, 0, stream>>>(stats + 512, stats + 640, bng + l * HD, bnb + l * HD, sc2, sh2, 128);
    k_bnapply<<<vec_blocks, 256, 0, stream>>>(zbuf, sc2, sh2, h, (l < NLAYERS - 1) ? 1 : 0);
  }

  hipMemsetAsync(psum, 0, (65536 + 512) * sizeof(float), stream);
  k_pool<<<vec_blocks, 256, 0, stream>>>(h, batch, psum, pcnt);
  k_final<<<NG, 128, 0, stream>>>(psum, pcnt, oW, ob, out);
}

// Round 3
// 1677.064 us; speedup vs baseline: 1.5211x; 1.1003x over previous
//
#include <hip/hip_runtime.h>

#define N_NODES 50000
#define N_EDGES 800000
#define HD 128
#define NLAYERS 5
#define EINC 16
#define NG 512

// ---------------- embedding: h[n][c] = emb[x[n]][c] ----------------
__global__ __launch_bounds__(256) void k_embed(const int* __restrict__ x,
                                               const float* __restrict__ emb,
                                               float* __restrict__ h) {
  int i = blockIdx.x * 256 + threadIdx.x;       // float4 index
  if (i < N_NODES * 32) {
    int n = i >> 5, cv = i & 31;
    *(float4*)&h[n * HD + cv * 4] = *(const float4*)&emb[x[n] * HD + cv * 4];
  }
}

// ---------------- CSR build ----------------
__global__ __launch_bounds__(256) void k_hist(const int* __restrict__ ei,
                                              int* __restrict__ deg) {
  int e = blockIdx.x * 256 + threadIdx.x;
  if (e < N_EDGES) atomicAdd(&deg[ei[N_EDGES + e]], 1);
}

__global__ __launch_bounds__(256) void k_scan1(const int* __restrict__ deg,
                                               int* __restrict__ incl,
                                               int* __restrict__ bsum) {
  __shared__ int s[256];
  int i = blockIdx.x * 256 + threadIdx.x;
  int v = (i < N_NODES) ? deg[i] : 0;
  s[threadIdx.x] = v;
  __syncthreads();
  for (int d = 1; d < 256; d <<= 1) {
    int t = (threadIdx.x >= d) ? s[threadIdx.x - d] : 0;
    __syncthreads();
    s[threadIdx.x] += t;
    __syncthreads();
  }
  if (i < N_NODES) incl[i] = s[threadIdx.x];
  if (threadIdx.x == 255) bsum[blockIdx.x] = s[255];
}

__global__ void k_scan2(int* __restrict__ bsum, int nb) {
  __shared__ int s[256];
  int v = (threadIdx.x < nb) ? bsum[threadIdx.x] : 0;
  s[threadIdx.x] = v;
  __syncthreads();
  for (int d = 1; d < 256; d <<= 1) {
    int t = (threadIdx.x >= d) ? s[threadIdx.x - d] : 0;
    __syncthreads();
    s[threadIdx.x] += t;
    __syncthreads();
  }
  if (threadIdx.x < nb) bsum[threadIdx.x] = s[threadIdx.x];
}

__global__ __launch_bounds__(256) void k_scan3(const int* __restrict__ deg,
                                               const int* __restrict__ incl,
                                               const int* __restrict__ bsum,
                                               int* __restrict__ offs,
                                               int* __restrict__ cursor) {
  int i = blockIdx.x * 256 + threadIdx.x;
  if (i < N_NODES) {
    int base = (blockIdx.x > 0) ? bsum[blockIdx.x - 1] : 0;
    int start = base + incl[i] - deg[i];
    offs[i] = start;
    cursor[i] = start;
    if (i == N_NODES - 1) offs[N_NODES] = N_EDGES;
  }
}

__global__ __launch_bounds__(256) void k_scatter(const int* __restrict__ ei,
                                                 const float* __restrict__ ea,
                                                 int* __restrict__ cursor,
                                                 int* __restrict__ srcs,
                                                 int* __restrict__ eids,
                                                 float* __restrict__ ea_s,
                                                 int permuted) {
  int e = blockIdx.x * 256 + threadIdx.x;
  if (e < N_EDGES) {
    int dst = ei[N_EDGES + e];
    int pos = atomicAdd(&cursor[dst], 1);
    srcs[pos] = ei[e];
    eids[pos] = e;
    if (permuted) {
      float4 a0 = *(const float4*)&ea[(size_t)e * EINC];
      float4 a1 = *(const float4*)&ea[(size_t)e * EINC + 4];
      float4 a2 = *(const float4*)&ea[(size_t)e * EINC + 8];
      float4 a3 = *(const float4*)&ea[(size_t)e * EINC + 12];
      *(float4*)&ea_s[(size_t)pos * EINC] = a0;
      *(float4*)&ea_s[(size_t)pos * EINC + 4] = a1;
      *(float4*)&ea_s[(size_t)pos * EINC + 8] = a2;
      *(float4*)&ea_s[(size_t)pos * EINC + 12] = a3;
    }
  }
}

// -------- fused per-node aggregation: z = (1+eps)h + sum_in relu(h[src]+e) --------
// one wave per node; lane covers channels (lane, lane+64)
__global__ __launch_bounds__(256) void k_aggr(const int* __restrict__ offs,
                                              const int* __restrict__ srcs,
                                              const int* __restrict__ eids,
                                              const float* __restrict__ ea,
                                              const float* __restrict__ ea_s,
                                              const float* __restrict__ W,   // [16][128]
                                              const float* __restrict__ eb,  // [128]
                                              const float* __restrict__ epsA, int layer,
                                              const float* __restrict__ h,
                                              float* __restrict__ z,
                                              int permuted) {
  __shared__ float sW[EINC * HD];
  __shared__ float sEb[HD];
  for (int t = threadIdx.x; t < EINC * HD; t += 256) sW[t] = W[t];
  if (threadIdx.x < HD) sEb[threadIdx.x] = eb[threadIdx.x];
  __syncthreads();
  const int wid = threadIdx.x >> 6;
  const int lane = threadIdx.x & 63;
  int n = blockIdx.x * 4 + wid;
  if (n >= N_NODES) return;
  const float epsv = 1.0f + epsA[layer];
  int j0 = offs[n], j1 = offs[n + 1];
  float acc0 = epsv * h[n * HD + lane];
  float acc1 = epsv * h[n * HD + 64 + lane];
  for (int j = j0; j < j1; ++j) {
    int src = srcs[j];
    const float* earow = permuted ? &ea_s[(size_t)j * EINC] : &ea[(size_t)eids[j] * EINC];
    float eav = (lane < EINC) ? earow[lane] : 0.0f;
    float e0 = sEb[lane], e1 = sEb[lane + 64];
#pragma unroll
    for (int k = 0; k < EINC; ++k) {
      float a = __shfl(eav, k, 64);
      e0 += a * sW[k * HD + lane];
      e1 += a * sW[k * HD + lane + 64];
    }
    acc0 += fmaxf(h[src * HD + lane] + e0, 0.0f);
    acc1 += fmaxf(h[src * HD + 64 + lane] + e1, 0.0f);
  }
  z[n * HD + lane] = acc0;
  z[n * HD + 64 + lane] = acc1;
}

// ---------- GEMM1: y1 = z @ W[128,256] + b ; col stats ----------
__global__ __launch_bounds__(256) void k_gemm1(const float* __restrict__ z,
                                               const float* __restrict__ W,
                                               const float* __restrict__ bias,
                                               float* __restrict__ y1,
                                               float* __restrict__ gsum,
                                               float* __restrict__ gsq) {
  __shared__ float sm[32 * 68 + 32 * 256];
  float* sAT = sm;             // [k][row], stride 68
  float* sB = sm + 32 * 68;    // [k][c], stride 256
  const int tid = threadIdx.x;
  const int tx = tid & 15;
  const int ty = tid >> 4;
  const int n0 = blockIdx.x * 64;
  float acc[4][16];
#pragma unroll
  for (int r = 0; r < 4; ++r)
#pragma unroll
    for (int c = 0; c < 16; ++c) acc[r][c] = 0.0f;

  for (int k0 = 0; k0 < 128; k0 += 32) {
#pragma unroll
    for (int f = tid; f < 512; f += 256) {   // A: 64 rows x 32 k
      int row = f >> 3, cv = f & 7;
      int n = n0 + row;
      float4 zv = make_float4(0.f, 0.f, 0.f, 0.f);
      if (n < N_NODES) zv = *(const float4*)&z[n * HD + k0 + cv * 4];
      sAT[(cv * 4 + 0) * 68 + row] = zv.x;
      sAT[(cv * 4 + 1) * 68 + row] = zv.y;
      sAT[(cv * 4 + 2) * 68 + row] = zv.z;
      sAT[(cv * 4 + 3) * 68 + row] = zv.w;
    }
#pragma unroll
    for (int f = tid; f < 2048; f += 256) {  // B: 32 k x 256 c
      int row = f >> 6, cv = f & 63;
      *(float4*)&sB[row * 256 + cv * 4] = *(const float4*)&W[(k0 + row) * 256 + cv * 4];
    }
    __syncthreads();
#pragma unroll
    for (int kk = 0; kk < 32; ++kk) {
      float av[4];
      *(float4*)av = *(const float4*)&sAT[kk * 68 + ty * 4];
#pragma unroll
      for (int g2 = 0; g2 < 4; ++g2) {
        float bv[4];
        *(float4*)bv = *(const float4*)&sB[kk * 256 + g2 * 64 + tx * 4];
#pragma unroll
        for (int r = 0; r < 4; ++r)
#pragma unroll
          for (int j = 0; j < 4; ++j) acc[r][g2 * 4 + j] += av[r] * bv[j];
      }
    }
    __syncthreads();
  }
  float bs[16];
#pragma unroll
  for (int g2 = 0; g2 < 4; ++g2) *(float4*)&bs[g2 * 4] = *(const float4*)&bias[g2 * 64 + tx * 4];
  float s[16], q[16];
#pragma unroll
  for (int c = 0; c < 16; ++c) { s[c] = 0.f; q[c] = 0.f; }
#pragma unroll
  for (int r = 0; r < 4; ++r) {
    int n = n0 + ty * 4 + r;
    if (n < N_NODES) {
#pragma unroll
      for (int g2 = 0; g2 < 4; ++g2) {
        float v[4];
#pragma unroll
        for (int j = 0; j < 4; ++j) {
          v[j] = acc[r][g2 * 4 + j] + bs[g2 * 4 + j];
          s[g2 * 4 + j] += v[j];
          q[g2 * 4 + j] += v[j] * v[j];
        }
        *(float4*)&y1[(long long)n * 256 + g2 * 64 + tx * 4] = *(float4*)v;
      }
    }
  }
  __syncthreads();  // smem reuse
#pragma unroll
  for (int g2 = 0; g2 < 4; ++g2) {
    *(float4*)&sm[ty * 256 + g2 * 64 + tx * 4] = *(float4*)&s[g2 * 4];
    *(float4*)&sm[4096 + ty * 256 + g2 * 64 + tx * 4] = *(float4*)&q[g2 * 4];
  }
  __syncthreads();
  {
    int c = tid;
    float sv = 0.f, qv = 0.f;
#pragma unroll
    for (int t = 0; t < 16; ++t) { sv += sm[t * 256 + c]; qv += sm[4096 + t * 256 + c]; }
    unsafeAtomicAdd(&gsum[c], sv);
    unsafeAtomicAdd(&gsq[c], qv);
  }
}

// ---------- GEMM2: y2 = relu(y1*sc+sh) @ W[256,128] + b ; col stats ----------
__global__ __launch_bounds__(256) void k_gemm2(const float* __restrict__ y1,
                                               const float* __restrict__ sc,
                                               const float* __restrict__ sh,
                                               const float* __restrict__ W,
                                               const float* __restrict__ bias,
                                               float* __restrict__ y2,
                                               float* __restrict__ gsum,
                                               float* __restrict__ gsq) {
  __shared__ float sm[32 * 68 + 32 * 128];
  float* sAT = sm;
  float* sB = sm + 32 * 68;
  const int tid = threadIdx.x;
  const int tx = tid & 15;
  const int ty = tid >> 4;
  const int n0 = blockIdx.x * 64;
  float acc[4][8];
#pragma unroll
  for (int r = 0; r < 4; ++r)
#pragma unroll
    for (int c = 0; c < 8; ++c) acc[r][c] = 0.0f;

  for (int k0 = 0; k0 < 256; k0 += 32) {
#pragma unroll
    for (int f = tid; f < 512; f += 256) {
      int row = f >> 3, cv = f & 7;
      int n = n0 + row;
      float4 zv = make_float4(0.f, 0.f, 0.f, 0.f);
      if (n < N_NODES) {
        float4 yv = *(const float4*)&y1[(long long)n * 256 + k0 + cv * 4];
        float4 scv = *(const float4*)&sc[k0 + cv * 4];
        float4 shv = *(const float4*)&sh[k0 + cv * 4];
        zv.x = fmaxf(yv.x * scv.x + shv.x, 0.f);
        zv.y = fmaxf(yv.y * scv.y + shv.y, 0.f);
        zv.z = fmaxf(yv.z * scv.z + shv.z, 0.f);
        zv.w = fmaxf(yv.w * scv.w + shv.w, 0.f);
      }
      sAT[(cv * 4 + 0) * 68 + row] = zv.x;
      sAT[(cv * 4 + 1) * 68 + row] = zv.y;
      sAT[(cv * 4 + 2) * 68 + row] = zv.z;
      sAT[(cv * 4 + 3) * 68 + row] = zv.w;
    }
#pragma unroll
    for (int f = tid; f < 1024; f += 256) {
      int row = f >> 5, cv = f & 31;
      *(float4*)&sB[row * 128 + cv * 4] = *(const float4*)&W[(k0 + row) * 128 + cv * 4];
    }
    __syncthreads();
#pragma unroll
    for (int kk = 0; kk < 32; ++kk) {
      float av[4];
      *(float4*)av = *(const float4*)&sAT[kk * 68 + ty * 4];
#pragma unroll
      for (int g2 = 0; g2 < 2; ++g2) {
        float bv[4];
        *(float4*)bv = *(const float4*)&sB[kk * 128 + g2 * 64 + tx * 4];
#pragma unroll
        for (int r = 0; r < 4; ++r)
#pragma unroll
          for (int j = 0; j < 4; ++j) acc[r][g2 * 4 + j] += av[r] * bv[j];
      }
    }
    __syncthreads();
  }
  float bs[8];
#pragma unroll
  for (int g2 = 0; g2 < 2; ++g2) *(float4*)&bs[g2 * 4] = *(const float4*)&bias[g2 * 64 + tx * 4];
  float s[8], q[8];
#pragma unroll
  for (int c = 0; c < 8; ++c) { s[c] = 0.f; q[c] = 0.f; }
#pragma unroll
  for (int r = 0; r < 4; ++r) {
    int n = n0 + ty * 4 + r;
    if (n < N_NODES) {
#pragma unroll
      for (int g2 = 0; g2 < 2; ++g2) {
        float v[4];
#pragma unroll
        for (int j = 0; j < 4; ++j) {
          v[j] = acc[r][g2 * 4 + j] + bs[g2 * 4 + j];
          s[g2 * 4 + j] += v[j];
          q[g2 * 4 + j] += v[j] * v[j];
        }
        *(float4*)&y2[(long long)n * HD + g2 * 64 + tx * 4] = *(float4*)v;
      }
    }
  }
  __syncthreads();
#pragma unroll
  for (int g2 = 0; g2 < 2; ++g2) {
    *(float4*)&sm[ty * 128 + g2 * 64 + tx * 4] = *(float4*)&s[g2 * 4];
    *(float4*)&sm[2048 + ty * 128 + g2 * 64 + tx * 4] = *(float4*)&q[g2 * 4];
  }
  __syncthreads();
  if (tid < 128) {
    int c = tid;
    float sv = 0.f, qv = 0.f;
#pragma unroll
    for (int t = 0; t < 16; ++t) { sv += sm[t * 128 + c]; qv += sm[2048 + t * 128 + c]; }
    unsafeAtomicAdd(&gsum[c], sv);
    unsafeAtomicAdd(&gsq[c], qv);
  }
}

// ---------------- BN finalize: stats -> scale/shift ----------------
__global__ void k_bnfin(const float* __restrict__ sum, const float* __restrict__ sq,
                        const float* __restrict__ g, const float* __restrict__ b,
                        float* __restrict__ sc, float* __restrict__ sh, int C) {
  int c = blockIdx.x * blockDim.x + threadIdx.x;
  if (c < C) {
    const float invN = 1.0f / (float)N_NODES;
    float m = sum[c] * invN;
    float v = fmaxf(sq[c] * invN - m * m, 0.0f);
    float rs = rsqrtf(v + 1e-5f);
    float scale = g[c] * rs;
    sc[c] = scale;
    sh[c] = b[c] - m * scale;
  }
}

// ---------------- apply BN (+optional relu) ----------------
__global__ __launch_bounds__(256) void k_bnapply(const float* __restrict__ y2,
                                                 const float* __restrict__ sc,
                                                 const float* __restrict__ sh,
                                                 float* __restrict__ h, int dorelu) {
  int i = blockIdx.x * 256 + threadIdx.x;
  if (i < N_NODES * 32) {
    int cv = i & 31;
    float4 v = *(const float4*)&y2[i * 4];
    float4 s4 = *(const float4*)&sc[cv * 4];
    float4 h4 = *(const float4*)&sh[cv * 4];
    float4 o;
    o.x = v.x * s4.x + h4.x; o.y = v.y * s4.y + h4.y;
    o.z = v.z * s4.z + h4.z; o.w = v.w * s4.w + h4.w;
    if (dorelu) {
      o.x = fmaxf(o.x, 0.f); o.y = fmaxf(o.y, 0.f);
      o.z = fmaxf(o.z, 0.f); o.w = fmaxf(o.w, 0.f);
    }
    *(float4*)&h[i * 4] = o;
  }
}

// ---------------- pooling: sorted-batch segment reduction ----------------
__global__ void k_goff(const int* __restrict__ batch, int* __restrict__ goff) {
  int g = blockIdx.x * blockDim.x + threadIdx.x;
  if (g <= NG) {
    if (g == NG) { goff[g] = N_NODES; return; }
    int lo = 0, hi = N_NODES;
    while (lo < hi) { int mid = (lo + hi) >> 1; if (batch[mid] < g) lo = mid + 1; else hi = mid; }
    goff[g] = lo;
  }
}

// one block per graph: 256 threads = 2 row-groups x 128 channels; fused mean
__global__ __launch_bounds__(256) void k_poolseg(const float* __restrict__ h,
                                                 const int* __restrict__ goff,
                                                 float* __restrict__ pooled) {
  __shared__ float sred[256];
  int g = blockIdx.x;
  int c = threadIdx.x & 127;
  int half = threadIdx.x >> 7;
  int n0 = goff[g], n1 = goff[g + 1];
  float s = 0.f;
  for (int n = n0 + half; n < n1; n += 2) s += h[(size_t)n * HD + c];
  sred[threadIdx.x] = s;
  __syncthreads();
  if (threadIdx.x < 128) {
    float tot = sred[threadIdx.x] + sred[threadIdx.x + 128];
    float cntf = (float)(n1 - n0);
    pooled[g * HD + threadIdx.x] = tot / fmaxf(cntf, 1.0f);
  }
}

// ---------------- final GEMM: out = pooled @ out_W + out_b ----------------
__global__ __launch_bounds__(128) void k_final(const float* __restrict__ pooled,
                                               const float* __restrict__ oW,
                                               const float* __restrict__ ob,
                                               float* __restrict__ out) {
  __shared__ float sP[HD];
  int g = blockIdx.x;
  int c = threadIdx.x;
  sP[c] = pooled[g * HD + c];
  __syncthreads();
  float acc = ob[c];
#pragma unroll 8
  for (int k = 0; k < HD; ++k) acc += sP[k] * oW[k * HD + c];
  out[g * HD + c] = acc;
}

extern "C" void kernel_launch(void* const* d_in, const int* in_sizes, int n_in,
                              void* d_out, int out_size, void* d_ws, size_t ws_size,
                              hipStream_t stream) {
  const int* x = (const int*)d_in[0];
  const int* ei = (const int*)d_in[1];
  const float* ea = (const float*)d_in[2];
  const int* batch = (const int*)d_in[3];
  const float* emb = (const float*)d_in[4];
  const float* eW = (const float*)d_in[5];
  const float* eb = (const float*)d_in[6];
  const float* epsA = (const float*)d_in[7];
  const float* W1 = (const float*)d_in[8];
  const float* b1 = (const float*)d_in[9];
  const float* g1 = (const float*)d_in[10];
  const float* be1 = (const float*)d_in[11];
  const float* W2 = (const float*)d_in[12];
  const float* b2 = (const float*)d_in[13];
  const float* bng = (const float*)d_in[14];
  const float* bnb = (const float*)d_in[15];
  const float* oW = (const float*)d_in[16];
  const float* ob = (const float*)d_in[17];
  float* out = (float*)d_out;

  // ----- workspace layout: ints first, then floats -----
  int* ip = (int*)d_ws;
  int* deg = ip;                         // 50,000
  int* incl = deg + 50000;               // 50,000
  int* offs = incl + 50000;              // 50,001
  int* cursor = offs + 50001;            // 50,000
  int* srcs = cursor + 50000;            // 800,000
  int* eids = srcs + 800000;             // 800,000
  int* bsum = eids + 800000;             // 196
  int* goff = bsum + 200;                // 513
  float* fp = (float*)(ip + 1800916);    // aligned float region
  float* h = fp;                         // 6,400,000
  float* zbuf = h + 6400000;             // 6,400,000 (z and y2 alias)
  float* y1 = zbuf + 6400000;            // 12,800,000
  float* stats = y1 + 12800000;          // 768
  float* sc1 = stats + 768;              // 256
  float* sh1 = sc1 + 256;                // 256
  float* sc2 = sh1 + 256;                // 128
  float* sh2 = sc2 + 128;                // 128
  float* pooled = sh2 + 128;             // 65,536
  float* ea_s = pooled + 65536;          // 12,800,000 (optional)

  size_t needed_with = (size_t)(ea_s + 12800000 - (float*)d_ws) * 4;
  int permuted = (ws_size >= needed_with) ? 1 : 0;

  const int vec_blocks = (N_NODES * 32 + 255) / 256;
  const int edge_blocks = (N_EDGES + 255) / 256;
  const int node_blocks = (N_NODES + 255) / 256;

  k_embed<<<vec_blocks, 256, 0, stream>>>(x, emb, h);

  // CSR build (once per launch)
  hipMemsetAsync(deg, 0, 50000 * sizeof(int), stream);
  k_hist<<<edge_blocks, 256, 0, stream>>>(ei, deg);
  k_scan1<<<node_blocks, 256, 0, stream>>>(deg, incl, bsum);
  k_scan2<<<1, 256, 0, stream>>>(bsum, node_blocks);
  k_scan3<<<node_blocks, 256, 0, stream>>>(deg, incl, bsum, offs, cursor);
  k_scatter<<<edge_blocks, 256, 0, stream>>>(ei, ea, cursor, srcs, eids, ea_s, permuted);
  k_goff<<<3, 256, 0, stream>>>(batch, goff);

  for (int l = 0; l < NLAYERS; ++l) {
    hipMemsetAsync(stats, 0, 768 * sizeof(float), stream);
    k_aggr<<<(N_NODES + 3) / 4, 256, 0, stream>>>(offs, srcs, eids, ea, ea_s,
                                                  eW + (size_t)l * EINC * HD, eb + l * HD,
                                                  epsA, l, h, zbuf, permuted);
    k_gemm1<<<(N_NODES + 63) / 64, 256, 0, stream>>>(zbuf, W1 + (size_t)l * 128 * 256,
                                                     b1 + l * 256, y1, stats, stats + 256);
    k_bnfin<<<1, 256, 0, stream>>>(stats, stats + 256, g1 + l * 256, be1 + l * 256, sc1, sh1, 256);
    k_gemm2<<<(N_NODES + 63) / 64, 256, 0, stream>>>(y1, sc1, sh1, W2 + (size_t)l * 256 * 128,
                                                     b2 + l * HD, zbuf, stats + 512, stats + 640);
    k_bnfin<<<1, 128, 0, stream>>>(stats + 512, stats + 640, bng + l * HD, bnb + l * HD, sc2, sh2, 128);
    k_bnapply<<<vec_blocks, 256, 0, stream>>>(zbuf, sc2, sh2, h, (l < NLAYERS - 1) ? 1 : 0);
  }

  k_poolseg<<<NG, 256, 0, stream>>>(h, goff, pooled);
  k_final<<<NG, 128, 0, stream>>>(pooled, oW, ob, out);
}

// Round 4
// 1348.112 us; speedup vs baseline: 1.8923x; 1.2440x over previous
//
#include <hip/hip_runtime.h>

#define N_NODES 50000
#define N_EDGES 800000
#define HD 128
#define NLAYERS 5
#define EINC 16
#define NG 512

// ---------------- embedding: h[n][c] = emb[x[n]][c] ----------------
__global__ __launch_bounds__(256) void k_embed(const int* __restrict__ x,
                                               const float* __restrict__ emb,
                                               float* __restrict__ h) {
  int i = blockIdx.x * 256 + threadIdx.x;       // float4 index
  if (i < N_NODES * 32) {
    int n = i >> 5, cv = i & 31;
    *(float4*)&h[n * HD + cv * 4] = *(const float4*)&emb[x[n] * HD + cv * 4];
  }
}

// ---------------- CSR build ----------------
__global__ __launch_bounds__(256) void k_hist(const int* __restrict__ ei,
                                              int* __restrict__ deg) {
  int e = blockIdx.x * 256 + threadIdx.x;
  if (e < N_EDGES) atomicAdd(&deg[ei[N_EDGES + e]], 1);
}

__global__ __launch_bounds__(256) void k_scan1(const int* __restrict__ deg,
                                               int* __restrict__ incl,
                                               int* __restrict__ bsum) {
  __shared__ int s[256];
  int i = blockIdx.x * 256 + threadIdx.x;
  int v = (i < N_NODES) ? deg[i] : 0;
  s[threadIdx.x] = v;
  __syncthreads();
  for (int d = 1; d < 256; d <<= 1) {
    int t = (threadIdx.x >= d) ? s[threadIdx.x - d] : 0;
    __syncthreads();
    s[threadIdx.x] += t;
    __syncthreads();
  }
  if (i < N_NODES) incl[i] = s[threadIdx.x];
  if (threadIdx.x == 255) bsum[blockIdx.x] = s[255];
}

__global__ void k_scan2(int* __restrict__ bsum, int nb) {
  __shared__ int s[256];
  int v = (threadIdx.x < nb) ? bsum[threadIdx.x] : 0;
  s[threadIdx.x] = v;
  __syncthreads();
  for (int d = 1; d < 256; d <<= 1) {
    int t = (threadIdx.x >= d) ? s[threadIdx.x - d] : 0;
    __syncthreads();
    s[threadIdx.x] += t;
    __syncthreads();
  }
  if (threadIdx.x < nb) bsum[threadIdx.x] = s[threadIdx.x];
}

__global__ __launch_bounds__(256) void k_scan3(const int* __restrict__ deg,
                                               const int* __restrict__ incl,
                                               const int* __restrict__ bsum,
                                               int* __restrict__ offs,
                                               int* __restrict__ cursor) {
  int i = blockIdx.x * 256 + threadIdx.x;
  if (i < N_NODES) {
    int base = (blockIdx.x > 0) ? bsum[blockIdx.x - 1] : 0;
    int start = base + incl[i] - deg[i];
    offs[i] = start;
    cursor[i] = start;
    if (i == N_NODES - 1) offs[N_NODES] = N_EDGES;
  }
}

__global__ __launch_bounds__(256) void k_scatter(const int* __restrict__ ei,
                                                 const float* __restrict__ ea,
                                                 int* __restrict__ cursor,
                                                 int* __restrict__ srcs,
                                                 int* __restrict__ eids,
                                                 float* __restrict__ ea_s,
                                                 int permuted) {
  int e = blockIdx.x * 256 + threadIdx.x;
  if (e < N_EDGES) {
    int dst = ei[N_EDGES + e];
    int pos = atomicAdd(&cursor[dst], 1);
    srcs[pos] = ei[e];
    eids[pos] = e;
    if (permuted) {
      float4 a0 = *(const float4*)&ea[(size_t)e * EINC];
      float4 a1 = *(const float4*)&ea[(size_t)e * EINC + 4];
      float4 a2 = *(const float4*)&ea[(size_t)e * EINC + 8];
      float4 a3 = *(const float4*)&ea[(size_t)e * EINC + 12];
      *(float4*)&ea_s[(size_t)pos * EINC] = a0;
      *(float4*)&ea_s[(size_t)pos * EINC + 4] = a1;
      *(float4*)&ea_s[(size_t)pos * EINC + 8] = a2;
      *(float4*)&ea_s[(size_t)pos * EINC + 12] = a3;
    }
  }
}

// -------- fused per-node aggregation: z = (1+eps)h + sum_in relu(h[src]+e) --------
// one wave per node; lane covers channels (lane, lane+64).
// W columns live in VGPRs; ea rows load via wave-uniform (scalar) reads -> zero DS ops.
__global__ __launch_bounds__(256) void k_aggr(const int* __restrict__ offs,
                                              const int* __restrict__ srcs,
                                              const int* __restrict__ eids,
                                              const float* __restrict__ ea,
                                              const float* __restrict__ ea_s,
                                              const float* __restrict__ W,   // [16][128]
                                              const float* __restrict__ eb,  // [128]
                                              const float* __restrict__ epsA, int layer,
                                              const float* __restrict__ h,
                                              float* __restrict__ z,
                                              int permuted) {
  const int wid = threadIdx.x >> 6;
  const int lane = threadIdx.x & 63;
  int n = blockIdx.x * 4 + wid;
  if (n >= N_NODES) return;

  float w0[EINC], w1[EINC];
#pragma unroll
  for (int k = 0; k < EINC; ++k) {
    w0[k] = W[k * HD + lane];
    w1[k] = W[k * HD + 64 + lane];
  }
  const float eb0 = eb[lane], eb1 = eb[lane + 64];
  const float epsv = 1.0f + epsA[layer];

  int j0 = offs[n], j1 = offs[n + 1];
  float acc0 = epsv * h[(size_t)n * HD + lane];
  float acc1 = epsv * h[(size_t)n * HD + 64 + lane];

  int j = j0;
  if (permuted) {
    for (; j + 1 < j1; j += 2) {
      int js = __builtin_amdgcn_readfirstlane(j);
      const float* ra = &ea_s[(size_t)js * EINC];
      int srcA = srcs[j], srcB = srcs[j + 1];
      float hA0 = h[(size_t)srcA * HD + lane];
      float hA1 = h[(size_t)srcA * HD + 64 + lane];
      float hB0 = h[(size_t)srcB * HD + lane];
      float hB1 = h[(size_t)srcB * HD + 64 + lane];
      float eA0 = eb0, eA1 = eb1, eB0 = eb0, eB1 = eb1;
#pragma unroll
      for (int k = 0; k < EINC; ++k) {
        float aA = ra[k];
        float aB = ra[EINC + k];
        eA0 += aA * w0[k]; eA1 += aA * w1[k];
        eB0 += aB * w0[k]; eB1 += aB * w1[k];
      }
      acc0 += fmaxf(hA0 + eA0, 0.0f) + fmaxf(hB0 + eB0, 0.0f);
      acc1 += fmaxf(hA1 + eA1, 0.0f) + fmaxf(hB1 + eB1, 0.0f);
    }
    for (; j < j1; ++j) {
      int js = __builtin_amdgcn_readfirstlane(j);
      const float* ra = &ea_s[(size_t)js * EINC];
      int src = srcs[j];
      float h0 = h[(size_t)src * HD + lane];
      float h1 = h[(size_t)src * HD + 64 + lane];
      float e0 = eb0, e1 = eb1;
#pragma unroll
      for (int k = 0; k < EINC; ++k) {
        float a = ra[k];
        e0 += a * w0[k]; e1 += a * w1[k];
      }
      acc0 += fmaxf(h0 + e0, 0.0f);
      acc1 += fmaxf(h1 + e1, 0.0f);
    }
  } else {
    for (; j < j1; ++j) {
      int eid = __builtin_amdgcn_readfirstlane(eids[j]);
      const float* ra = &ea[(size_t)eid * EINC];
      int src = srcs[j];
      float h0 = h[(size_t)src * HD + lane];
      float h1 = h[(size_t)src * HD + 64 + lane];
      float e0 = eb0, e1 = eb1;
#pragma unroll
      for (int k = 0; k < EINC; ++k) {
        float a = ra[k];
        e0 += a * w0[k]; e1 += a * w1[k];
      }
      acc0 += fmaxf(h0 + e0, 0.0f);
      acc1 += fmaxf(h1 + e1, 0.0f);
    }
  }
  z[(size_t)n * HD + lane] = acc0;
  z[(size_t)n * HD + 64 + lane] = acc1;
}

// ---------- GEMM1: y1 = z @ W[128,256] + b ; col stats ----------
__global__ __launch_bounds__(256) void k_gemm1(const float* __restrict__ z,
                                               const float* __restrict__ W,
                                               const float* __restrict__ bias,
                                               float* __restrict__ y1,
                                               float* __restrict__ gsum,
                                               float* __restrict__ gsq) {
  __shared__ float sm[32 * 68 + 32 * 256];
  float* sAT = sm;             // [k][row], stride 68
  float* sB = sm + 32 * 68;    // [k][c], stride 256
  const int tid = threadIdx.x;
  const int tx = tid & 15;
  const int ty = tid >> 4;
  const int n0 = blockIdx.x * 64;
  float acc[4][16];
#pragma unroll
  for (int r = 0; r < 4; ++r)
#pragma unroll
    for (int c = 0; c < 16; ++c) acc[r][c] = 0.0f;

  for (int k0 = 0; k0 < 128; k0 += 32) {
#pragma unroll
    for (int f = tid; f < 512; f += 256) {   // A: 64 rows x 32 k
      int row = f >> 3, cv = f & 7;
      int n = n0 + row;
      float4 zv = make_float4(0.f, 0.f, 0.f, 0.f);
      if (n < N_NODES) zv = *(const float4*)&z[n * HD + k0 + cv * 4];
      sAT[(cv * 4 + 0) * 68 + row] = zv.x;
      sAT[(cv * 4 + 1) * 68 + row] = zv.y;
      sAT[(cv * 4 + 2) * 68 + row] = zv.z;
      sAT[(cv * 4 + 3) * 68 + row] = zv.w;
    }
#pragma unroll
    for (int f = tid; f < 2048; f += 256) {  // B: 32 k x 256 c
      int row = f >> 6, cv = f & 63;
      *(float4*)&sB[row * 256 + cv * 4] = *(const float4*)&W[(k0 + row) * 256 + cv * 4];
    }
    __syncthreads();
#pragma unroll
    for (int kk = 0; kk < 32; ++kk) {
      float av[4];
      *(float4*)av = *(const float4*)&sAT[kk * 68 + ty * 4];
#pragma unroll
      for (int g2 = 0; g2 < 4; ++g2) {
        float bv[4];
        *(float4*)bv = *(const float4*)&sB[kk * 256 + g2 * 64 + tx * 4];
#pragma unroll
        for (int r = 0; r < 4; ++r)
#pragma unroll
          for (int j = 0; j < 4; ++j) acc[r][g2 * 4 + j] += av[r] * bv[j];
      }
    }
    __syncthreads();
  }
  float bs[16];
#pragma unroll
  for (int g2 = 0; g2 < 4; ++g2) *(float4*)&bs[g2 * 4] = *(const float4*)&bias[g2 * 64 + tx * 4];
  float s[16], q[16];
#pragma unroll
  for (int c = 0; c < 16; ++c) { s[c] = 0.f; q[c] = 0.f; }
#pragma unroll
  for (int r = 0; r < 4; ++r) {
    int n = n0 + ty * 4 + r;
    if (n < N_NODES) {
#pragma unroll
      for (int g2 = 0; g2 < 4; ++g2) {
        float v[4];
#pragma unroll
        for (int j = 0; j < 4; ++j) {
          v[j] = acc[r][g2 * 4 + j] + bs[g2 * 4 + j];
          s[g2 * 4 + j] += v[j];
          q[g2 * 4 + j] += v[j] * v[j];
        }
        *(float4*)&y1[(long long)n * 256 + g2 * 64 + tx * 4] = *(float4*)v;
      }
    }
  }
  __syncthreads();  // smem reuse
#pragma unroll
  for (int g2 = 0; g2 < 4; ++g2) {
    *(float4*)&sm[ty * 256 + g2 * 64 + tx * 4] = *(float4*)&s[g2 * 4];
    *(float4*)&sm[4096 + ty * 256 + g2 * 64 + tx * 4] = *(float4*)&q[g2 * 4];
  }
  __syncthreads();
  {
    int c = tid;
    float sv = 0.f, qv = 0.f;
#pragma unroll
    for (int t = 0; t < 16; ++t) { sv += sm[t * 256 + c]; qv += sm[4096 + t * 256 + c]; }
    unsafeAtomicAdd(&gsum[c], sv);
    unsafeAtomicAdd(&gsq[c], qv);
  }
}

// ---------- GEMM2: y2 = relu(y1*sc+sh) @ W[256,128] + b ; col stats ----------
__global__ __launch_bounds__(256) void k_gemm2(const float* __restrict__ y1,
                                               const float* __restrict__ sc,
                                               const float* __restrict__ sh,
                                               const float* __restrict__ W,
                                               const float* __restrict__ bias,
                                               float* __restrict__ y2,
                                               float* __restrict__ gsum,
                                               float* __restrict__ gsq) {
  __shared__ float sm[32 * 68 + 32 * 128];
  float* sAT = sm;
  float* sB = sm + 32 * 68;
  const int tid = threadIdx.x;
  const int tx = tid & 15;
  const int ty = tid >> 4;
  const int n0 = blockIdx.x * 64;
  float acc[4][8];
#pragma unroll
  for (int r = 0; r < 4; ++r)
#pragma unroll
    for (int c = 0; c < 8; ++c) acc[r][c] = 0.0f;

  for (int k0 = 0; k0 < 256; k0 += 32) {
#pragma unroll
    for (int f = tid; f < 512; f += 256) {
      int row = f >> 3, cv = f & 7;
      int n = n0 + row;
      float4 zv = make_float4(0.f, 0.f, 0.f, 0.f);
      if (n < N_NODES) {
        float4 yv = *(const float4*)&y1[(long long)n * 256 + k0 + cv * 4];
        float4 scv = *(const float4*)&sc[k0 + cv * 4];
        float4 shv = *(const float4*)&sh[k0 + cv * 4];
        zv.x = fmaxf(yv.x * scv.x + shv.x, 0.f);
        zv.y = fmaxf(yv.y * scv.y + shv.y, 0.f);
        zv.z = fmaxf(yv.z * scv.z + shv.z, 0.f);
        zv.w = fmaxf(yv.w * scv.w + shv.w, 0.f);
      }
      sAT[(cv * 4 + 0) * 68 + row] = zv.x;
      sAT[(cv * 4 + 1) * 68 + row] = zv.y;
      sAT[(cv * 4 + 2) * 68 + row] = zv.z;
      sAT[(cv * 4 + 3) * 68 + row] = zv.w;
    }
#pragma unroll
    for (int f = tid; f < 1024; f += 256) {
      int row = f >> 5, cv = f & 31;
      *(float4*)&sB[row * 128 + cv * 4] = *(const float4*)&W[(k0 + row) * 128 + cv * 4];
    }
    __syncthreads();
#pragma unroll
    for (int kk = 0; kk < 32; ++kk) {
      float av[4];
      *(float4*)av = *(const float4*)&sAT[kk * 68 + ty * 4];
#pragma unroll
      for (int g2 = 0; g2 < 2; ++g2) {
        float bv[4];
        *(float4*)bv = *(const float4*)&sB[kk * 128 + g2 * 64 + tx * 4];
#pragma unroll
        for (int r = 0; r < 4; ++r)
#pragma unroll
          for (int j = 0; j < 4; ++j) acc[r][g2 * 4 + j] += av[r] * bv[j];
      }
    }
    __syncthreads();
  }
  float bs[8];
#pragma unroll
  for (int g2 = 0; g2 < 2; ++g2) *(float4*)&bs[g2 * 4] = *(const float4*)&bias[g2 * 64 + tx * 4];
  float s[8], q[8];
#pragma unroll
  for (int c = 0; c < 8; ++c) { s[c] = 0.f; q[c] = 0.f; }
#pragma unroll
  for (int r = 0; r < 4; ++r) {
    int n = n0 + ty * 4 + r;
    if (n < N_NODES) {
#pragma unroll
      for (int g2 = 0; g2 < 2; ++g2) {
        float v[4];
#pragma unroll
        for (int j = 0; j < 4; ++j) {
          v[j] = acc[r][g2 * 4 + j] + bs[g2 * 4 + j];
          s[g2 * 4 + j] += v[j];
          q[g2 * 4 + j] += v[j] * v[j];
        }
        *(float4*)&y2[(long long)n * HD + g2 * 64 + tx * 4] = *(float4*)v;
      }
    }
  }
  __syncthreads();
#pragma unroll
  for (int g2 = 0; g2 < 2; ++g2) {
    *(float4*)&sm[ty * 128 + g2 * 64 + tx * 4] = *(float4*)&s[g2 * 4];
    *(float4*)&sm[2048 + ty * 128 + g2 * 64 + tx * 4] = *(float4*)&q[g2 * 4];
  }
  __syncthreads();
  if (tid < 128) {
    int c = tid;
    float sv = 0.f, qv = 0.f;
#pragma unroll
    for (int t = 0; t < 16; ++t) { sv += sm[t * 128 + c]; qv += sm[2048 + t * 128 + c]; }
    unsafeAtomicAdd(&gsum[c], sv);
    unsafeAtomicAdd(&gsq[c], qv);
  }
}

// ---------------- BN finalize: stats -> scale/shift ----------------
__global__ void k_bnfin(const float* __restrict__ sum, const float* __restrict__ sq,
                        const float* __restrict__ g, const float* __restrict__ b,
                        float* __restrict__ sc, float* __restrict__ sh, int C) {
  int c = blockIdx.x * blockDim.x + threadIdx.x;
  if (c < C) {
    const float invN = 1.0f / (float)N_NODES;
    float m = sum[c] * invN;
    float v = fmaxf(sq[c] * invN - m * m, 0.0f);
    float rs = rsqrtf(v + 1e-5f);
    float scale = g[c] * rs;
    sc[c] = scale;
    sh[c] = b[c] - m * scale;
  }
}

// ---------------- apply BN (+optional relu) ----------------
__global__ __launch_bounds__(256) void k_bnapply(const float* __restrict__ y2,
                                                 const float* __restrict__ sc,
                                                 const float* __restrict__ sh,
                                                 float* __restrict__ h, int dorelu) {
  int i = blockIdx.x * 256 + threadIdx.x;
  if (i < N_NODES * 32) {
    int cv = i & 31;
    float4 v = *(const float4*)&y2[i * 4];
    float4 s4 = *(const float4*)&sc[cv * 4];
    float4 h4 = *(const float4*)&sh[cv * 4];
    float4 o;
    o.x = v.x * s4.x + h4.x; o.y = v.y * s4.y + h4.y;
    o.z = v.z * s4.z + h4.z; o.w = v.w * s4.w + h4.w;
    if (dorelu) {
      o.x = fmaxf(o.x, 0.f); o.y = fmaxf(o.y, 0.f);
      o.z = fmaxf(o.z, 0.f); o.w = fmaxf(o.w, 0.f);
    }
    *(float4*)&h[i * 4] = o;
  }
}

// ---------------- pooling: sorted-batch segment reduction ----------------
__global__ void k_goff(const int* __restrict__ batch, int* __restrict__ goff) {
  int g = blockIdx.x * blockDim.x + threadIdx.x;
  if (g <= NG) {
    if (g == NG) { goff[g] = N_NODES; return; }
    int lo = 0, hi = N_NODES;
    while (lo < hi) { int mid = (lo + hi) >> 1; if (batch[mid] < g) lo = mid + 1; else hi = mid; }
    goff[g] = lo;
  }
}

// one block per graph: 256 threads = 2 row-groups x 128 channels; fused mean
__global__ __launch_bounds__(256) void k_poolseg(const float* __restrict__ h,
                                                 const int* __restrict__ goff,
                                                 float* __restrict__ pooled) {
  __shared__ float sred[256];
  int g = blockIdx.x;
  int c = threadIdx.x & 127;
  int half = threadIdx.x >> 7;
  int n0 = goff[g], n1 = goff[g + 1];
  float s = 0.f;
  for (int n = n0 + half; n < n1; n += 2) s += h[(size_t)n * HD + c];
  sred[threadIdx.x] = s;
  __syncthreads();
  if (threadIdx.x < 128) {
    float tot = sred[threadIdx.x] + sred[threadIdx.x + 128];
    float cntf = (float)(n1 - n0);
    pooled[g * HD + threadIdx.x] = tot / fmaxf(cntf, 1.0f);
  }
}

// ---------------- final GEMM: out = pooled @ out_W + out_b ----------------
__global__ __launch_bounds__(128) void k_final(const float* __restrict__ pooled,
                                               const float* __restrict__ oW,
                                               const float* __restrict__ ob,
                                               float* __restrict__ out) {
  __shared__ float sP[HD];
  int g = blockIdx.x;
  int c = threadIdx.x;
  sP[c] = pooled[g * HD + c];
  __syncthreads();
  float acc = ob[c];
#pragma unroll 8
  for (int k = 0; k < HD; ++k) acc += sP[k] * oW[k * HD + c];
  out[g * HD + c] = acc;
}

extern "C" void kernel_launch(void* const* d_in, const int* in_sizes, int n_in,
                              void* d_out, int out_size, void* d_ws, size_t ws_size,
                              hipStream_t stream) {
  const int* x = (const int*)d_in[0];
  const int* ei = (const int*)d_in[1];
  const float* ea = (const float*)d_in[2];
  const int* batch = (const int*)d_in[3];
  const float* emb = (const float*)d_in[4];
  const float* eW = (const float*)d_in[5];
  const float* eb = (const float*)d_in[6];
  const float* epsA = (const float*)d_in[7];
  const float* W1 = (const float*)d_in[8];
  const float* b1 = (const float*)d_in[9];
  const float* g1 = (const float*)d_in[10];
  const float* be1 = (const float*)d_in[11];
  const float* W2 = (const float*)d_in[12];
  const float* b2 = (const float*)d_in[13];
  const float* bng = (const float*)d_in[14];
  const float* bnb = (const float*)d_in[15];
  const float* oW = (const float*)d_in[16];
  const float* ob = (const float*)d_in[17];
  float* out = (float*)d_out;

  // ----- workspace layout: ints first, then floats -----
  int* ip = (int*)d_ws;
  int* deg = ip;                         // 50,000
  int* incl = deg + 50000;               // 50,000
  int* offs = incl + 50000;              // 50,001
  int* cursor = offs + 50001;            // 50,000
  int* srcs = cursor + 50000;            // 800,000
  int* eids = srcs + 800000;             // 800,000
  int* bsum = eids + 800000;             // 196
  int* goff = bsum + 200;                // 513
  float* fp = (float*)(ip + 1800916);    // aligned float region
  float* h = fp;                         // 6,400,000
  float* zbuf = h + 6400000;             // 6,400,000 (z and y2 alias)
  float* y1 = zbuf + 6400000;            // 12,800,000
  float* stats = y1 + 12800000;          // 768
  float* sc1 = stats + 768;              // 256
  float* sh1 = sc1 + 256;                // 256
  float* sc2 = sh1 + 256;                // 128
  float* sh2 = sc2 + 128;                // 128
  float* pooled = sh2 + 128;             // 65,536
  float* ea_s = pooled + 65536;          // 12,800,000 (optional)

  size_t needed_with = (size_t)(ea_s + 12800000 - (float*)d_ws) * 4;
  int permuted = (ws_size >= needed_with) ? 1 : 0;

  const int vec_blocks = (N_NODES * 32 + 255) / 256;
  const int edge_blocks = (N_EDGES + 255) / 256;
  const int node_blocks = (N_NODES + 255) / 256;

  k_embed<<<vec_blocks, 256, 0, stream>>>(x, emb, h);

  // CSR build (once per launch)
  hipMemsetAsync(deg, 0, 50000 * sizeof(int), stream);
  k_hist<<<edge_blocks, 256, 0, stream>>>(ei, deg);
  k_scan1<<<node_blocks, 256, 0, stream>>>(deg, incl, bsum);
  k_scan2<<<1, 256, 0, stream>>>(bsum, node_blocks);
  k_scan3<<<node_blocks, 256, 0, stream>>>(deg, incl, bsum, offs, cursor);
  k_scatter<<<edge_blocks, 256, 0, stream>>>(ei, ea, cursor, srcs, eids, ea_s, permuted);
  k_goff<<<3, 256, 0, stream>>>(batch, goff);

  for (int l = 0; l < NLAYERS; ++l) {
    hipMemsetAsync(stats, 0, 768 * sizeof(float), stream);
    k_aggr<<<(N_NODES + 3) / 4, 256, 0, stream>>>(offs, srcs, eids, ea, ea_s,
                                                  eW + (size_t)l * EINC * HD, eb + l * HD,
                                                  epsA, l, h, zbuf, permuted);
    k_gemm1<<<(N_NODES + 63) / 64, 256, 0, stream>>>(zbuf, W1 + (size_t)l * 128 * 256,
                                                     b1 + l * 256, y1, stats, stats + 256);
    k_bnfin<<<1, 256, 0, stream>>>(stats, stats + 256, g1 + l * 256, be1 + l * 256, sc1, sh1, 256);
    k_gemm2<<<(N_NODES + 63) / 64, 256, 0, stream>>>(y1, sc1, sh1, W2 + (size_t)l * 256 * 128,
                                                     b2 + l * HD, zbuf, stats + 512, stats + 640);
    k_bnfin<<<1, 128, 0, stream>>>(stats + 512, stats + 640, bng + l * HD, bnb + l * HD, sc2, sh2, 128);
    k_bnapply<<<vec_blocks, 256, 0, stream>>>(zbuf, sc2, sh2, h, (l < NLAYERS - 1) ? 1 : 0);
  }

  k_poolseg<<<NG, 256, 0, stream>>>(h, goff, pooled);
  k_final<<<NG, 128, 0, stream>>>(pooled, oW, ob, out);
}

// Round 5
// 1122.811 us; speedup vs baseline: 2.2720x; 1.2007x over previous
//
#include <hip/hip_runtime.h>
#include <hip/hip_fp16.h>

#define N_NODES 50000
#define N_EDGES 800000
#define HD 128
#define NLAYERS 5
#define EINC 16
#define NG 512

typedef _Float16 half8 __attribute__((ext_vector_type(8)));
typedef float f32x4 __attribute__((ext_vector_type(4)));

// ---------------- embedding ----------------
__global__ __launch_bounds__(256) void k_embed(const int* __restrict__ x,
                                               const float* __restrict__ emb,
                                               float* __restrict__ h) {
  int i = blockIdx.x * 256 + threadIdx.x;
  if (i < N_NODES * 32) {
    int n = i >> 5, cv = i & 31;
    *(float4*)&h[n * HD + cv * 4] = *(const float4*)&emb[x[n] * HD + cv * 4];
  }
}

// ---------------- CSR build ----------------
__global__ __launch_bounds__(256) void k_hist(const int* __restrict__ ei,
                                              int* __restrict__ deg) {
  int e = blockIdx.x * 256 + threadIdx.x;
  if (e < N_EDGES) atomicAdd(&deg[ei[N_EDGES + e]], 1);
}

__global__ __launch_bounds__(256) void k_scan1(const int* __restrict__ deg,
                                               int* __restrict__ incl,
                                               int* __restrict__ bsum) {
  __shared__ int s[256];
  int i = blockIdx.x * 256 + threadIdx.x;
  int v = (i < N_NODES) ? deg[i] : 0;
  s[threadIdx.x] = v;
  __syncthreads();
  for (int d = 1; d < 256; d <<= 1) {
    int t = (threadIdx.x >= d) ? s[threadIdx.x - d] : 0;
    __syncthreads();
    s[threadIdx.x] += t;
    __syncthreads();
  }
  if (i < N_NODES) incl[i] = s[threadIdx.x];
  if (threadIdx.x == 255) bsum[blockIdx.x] = s[255];
}

__global__ void k_scan2(int* __restrict__ bsum, int nb) {
  __shared__ int s[256];
  int v = (threadIdx.x < nb) ? bsum[threadIdx.x] : 0;
  s[threadIdx.x] = v;
  __syncthreads();
  for (int d = 1; d < 256; d <<= 1) {
    int t = (threadIdx.x >= d) ? s[threadIdx.x - d] : 0;
    __syncthreads();
    s[threadIdx.x] += t;
    __syncthreads();
  }
  if (threadIdx.x < nb) bsum[threadIdx.x] = s[threadIdx.x];
}

__global__ __launch_bounds__(256) void k_scan3(const int* __restrict__ deg,
                                               const int* __restrict__ incl,
                                               const int* __restrict__ bsum,
                                               int* __restrict__ offs,
                                               int* __restrict__ cursor) {
  int i = blockIdx.x * 256 + threadIdx.x;
  if (i < N_NODES) {
    int base = (blockIdx.x > 0) ? bsum[blockIdx.x - 1] : 0;
    int start = base + incl[i] - deg[i];
    offs[i] = start;
    cursor[i] = start;
    if (i == N_NODES - 1) offs[N_NODES] = N_EDGES;
  }
}

__global__ __launch_bounds__(256) void k_scatter(const int* __restrict__ ei,
                                                 const float* __restrict__ ea,
                                                 int* __restrict__ cursor,
                                                 int* __restrict__ srcs,
                                                 int* __restrict__ eids,
                                                 float* __restrict__ ea_s,
                                                 int permuted) {
  int e = blockIdx.x * 256 + threadIdx.x;
  if (e < N_EDGES) {
    int dst = ei[N_EDGES + e];
    int pos = atomicAdd(&cursor[dst], 1);
    srcs[pos] = ei[e];
    eids[pos] = e;
    if (permuted) {
      float4 a0 = *(const float4*)&ea[(size_t)e * EINC];
      float4 a1 = *(const float4*)&ea[(size_t)e * EINC + 4];
      float4 a2 = *(const float4*)&ea[(size_t)e * EINC + 8];
      float4 a3 = *(const float4*)&ea[(size_t)e * EINC + 12];
      *(float4*)&ea_s[(size_t)pos * EINC] = a0;
      *(float4*)&ea_s[(size_t)pos * EINC + 4] = a1;
      *(float4*)&ea_s[(size_t)pos * EINC + 8] = a2;
      *(float4*)&ea_s[(size_t)pos * EINC + 12] = a3;
    }
  }
}

// ---------------- weight convert+transpose to fp16 (once per launch) ----------------
__global__ __launch_bounds__(256) void k_cvtw1(const float* __restrict__ W1,
                                               _Float16* __restrict__ w1t) {
  // w1t[l][n][k] = W1[l][k][n], n<256, k<128
  int i = blockIdx.x * 256 + threadIdx.x;
  if (i < NLAYERS * 256 * 128) {
    int l = i >> 15, r = i & 32767;
    int n = r >> 7, k = r & 127;
    w1t[i] = (_Float16)W1[(size_t)l * 32768 + k * 256 + n];
  }
}
__global__ __launch_bounds__(256) void k_cvtw2(const float* __restrict__ W2,
                                               _Float16* __restrict__ w2t) {
  // w2t[l][n][k] = W2[l][k][n], n<128, k<256
  int i = blockIdx.x * 256 + threadIdx.x;
  if (i < NLAYERS * 128 * 256) {
    int l = i >> 15, r = i & 32767;
    int n = r >> 8, k = r & 255;
    w2t[i] = (_Float16)W2[(size_t)l * 32768 + k * 128 + n];
  }
}

// -------- fused per-node aggregation (unchanged from R3) --------
__global__ __launch_bounds__(256) void k_aggr(const int* __restrict__ offs,
                                              const int* __restrict__ srcs,
                                              const int* __restrict__ eids,
                                              const float* __restrict__ ea,
                                              const float* __restrict__ ea_s,
                                              const float* __restrict__ W,
                                              const float* __restrict__ eb,
                                              const float* __restrict__ epsA, int layer,
                                              const float* __restrict__ h,
                                              float* __restrict__ z,
                                              int permuted) {
  const int wid = threadIdx.x >> 6;
  const int lane = threadIdx.x & 63;
  int n = blockIdx.x * 4 + wid;
  if (n >= N_NODES) return;

  float w0[EINC], w1[EINC];
#pragma unroll
  for (int k = 0; k < EINC; ++k) {
    w0[k] = W[k * HD + lane];
    w1[k] = W[k * HD + 64 + lane];
  }
  const float eb0 = eb[lane], eb1 = eb[lane + 64];
  const float epsv = 1.0f + epsA[layer];

  int j0 = offs[n], j1 = offs[n + 1];
  float acc0 = epsv * h[(size_t)n * HD + lane];
  float acc1 = epsv * h[(size_t)n * HD + 64 + lane];

  int j = j0;
  if (permuted) {
    for (; j + 1 < j1; j += 2) {
      int js = __builtin_amdgcn_readfirstlane(j);
      const float* ra = &ea_s[(size_t)js * EINC];
      int srcA = srcs[j], srcB = srcs[j + 1];
      float hA0 = h[(size_t)srcA * HD + lane];
      float hA1 = h[(size_t)srcA * HD + 64 + lane];
      float hB0 = h[(size_t)srcB * HD + lane];
      float hB1 = h[(size_t)srcB * HD + 64 + lane];
      float eA0 = eb0, eA1 = eb1, eB0 = eb0, eB1 = eb1;
#pragma unroll
      for (int k = 0; k < EINC; ++k) {
        float aA = ra[k];
        float aB = ra[EINC + k];
        eA0 += aA * w0[k]; eA1 += aA * w1[k];
        eB0 += aB * w0[k]; eB1 += aB * w1[k];
      }
      acc0 += fmaxf(hA0 + eA0, 0.0f) + fmaxf(hB0 + eB0, 0.0f);
      acc1 += fmaxf(hA1 + eA1, 0.0f) + fmaxf(hB1 + eB1, 0.0f);
    }
    for (; j < j1; ++j) {
      int js = __builtin_amdgcn_readfirstlane(j);
      const float* ra = &ea_s[(size_t)js * EINC];
      int src = srcs[j];
      float h0 = h[(size_t)src * HD + lane];
      float h1 = h[(size_t)src * HD + 64 + lane];
      float e0 = eb0, e1 = eb1;
#pragma unroll
      for (int k = 0; k < EINC; ++k) {
        float a = ra[k];
        e0 += a * w0[k]; e1 += a * w1[k];
      }
      acc0 += fmaxf(h0 + e0, 0.0f);
      acc1 += fmaxf(h1 + e1, 0.0f);
    }
  } else {
    for (; j < j1; ++j) {
      int eid = __builtin_amdgcn_readfirstlane(eids[j]);
      const float* ra = &ea[(size_t)eid * EINC];
      int src = srcs[j];
      float h0 = h[(size_t)src * HD + lane];
      float h1 = h[(size_t)src * HD + 64 + lane];
      float e0 = eb0, e1 = eb1;
#pragma unroll
      for (int k = 0; k < EINC; ++k) {
        float a = ra[k];
        e0 += a * w0[k]; e1 += a * w1[k];
      }
      acc0 += fmaxf(h0 + e0, 0.0f);
      acc1 += fmaxf(h1 + e1, 0.0f);
    }
  }
  z[(size_t)n * HD + lane] = acc0;
  z[(size_t)n * HD + 64 + lane] = acc1;
}

// ---------- GEMM1 (MFMA fp16): y1h = fp16(z @ W1 + b1) ; col stats ----------
// block 256 thr = 4 waves (2x2), tile BM=128 x BN=128, K=128 in 4 steps of 32
__global__ __launch_bounds__(256) void k_gemm1m(const float* __restrict__ z,
                                                const _Float16* __restrict__ w1t, // [256][128]
                                                const float* __restrict__ bias,   // [256]
                                                _Float16* __restrict__ y1h,
                                                float* __restrict__ gsum,
                                                float* __restrict__ gsq) {
  __shared__ _Float16 sA[128 * 40];
  __shared__ _Float16 sBT[128 * 40];
  __shared__ float ssum[128], ssq[128];
  const int tid = threadIdx.x;
  const int lane = tid & 63;
  const int wid = tid >> 6;
  const int wm = wid >> 1, wn = wid & 1;
  const int m0 = blockIdx.x * 128;
  const int n0 = blockIdx.y * 128;

  if (tid < 128) { ssum[tid] = 0.f; ssq[tid] = 0.f; }

  f32x4 acc[4][4];
  const f32x4 zz = {0.f, 0.f, 0.f, 0.f};
#pragma unroll
  for (int a = 0; a < 4; ++a)
#pragma unroll
    for (int b = 0; b < 4; ++b) acc[a][b] = zz;

  const int srow = tid >> 1;           // 0..127
  const int skh = (tid & 1) * 16;      // 0 or 16

  for (int k0 = 0; k0 < 128; k0 += 32) {
    // ---- stage A (z fp32 -> fp16) ----
    {
      int n = m0 + srow;
      half8 p0, p1;
      if (n < N_NODES) {
        float4 a0 = *(const float4*)&z[(size_t)n * 128 + k0 + skh + 0];
        float4 a1 = *(const float4*)&z[(size_t)n * 128 + k0 + skh + 4];
        float4 a2 = *(const float4*)&z[(size_t)n * 128 + k0 + skh + 8];
        float4 a3 = *(const float4*)&z[(size_t)n * 128 + k0 + skh + 12];
        p0[0] = (_Float16)a0.x; p0[1] = (_Float16)a0.y; p0[2] = (_Float16)a0.z; p0[3] = (_Float16)a0.w;
        p0[4] = (_Float16)a1.x; p0[5] = (_Float16)a1.y; p0[6] = (_Float16)a1.z; p0[7] = (_Float16)a1.w;
        p1[0] = (_Float16)a2.x; p1[1] = (_Float16)a2.y; p1[2] = (_Float16)a2.z; p1[3] = (_Float16)a2.w;
        p1[4] = (_Float16)a3.x; p1[5] = (_Float16)a3.y; p1[6] = (_Float16)a3.z; p1[7] = (_Float16)a3.w;
      } else {
#pragma unroll
        for (int j = 0; j < 8; ++j) { p0[j] = (_Float16)0.f; p1[j] = (_Float16)0.f; }
      }
      *(half8*)&sA[srow * 40 + skh] = p0;
      *(half8*)&sA[srow * 40 + skh + 8] = p1;
    }
    // ---- stage B^T (w1t already [n][k] fp16) ----
    {
      half8 u0 = *(const half8*)&w1t[(size_t)(n0 + srow) * 128 + k0 + skh];
      half8 u1 = *(const half8*)&w1t[(size_t)(n0 + srow) * 128 + k0 + skh + 8];
      *(half8*)&sBT[srow * 40 + skh] = u0;
      *(half8*)&sBT[srow * 40 + skh + 8] = u1;
    }
    __syncthreads();
    half8 af[4], bf[4];
#pragma unroll
    for (int t = 0; t < 4; ++t) {
      af[t] = *(const half8*)&sA[(wm * 64 + t * 16 + (lane & 15)) * 40 + (lane >> 4) * 8];
      bf[t] = *(const half8*)&sBT[(wn * 64 + t * 16 + (lane & 15)) * 40 + (lane >> 4) * 8];
    }
#pragma unroll
    for (int tm = 0; tm < 4; ++tm)
#pragma unroll
      for (int tn = 0; tn < 4; ++tn)
        acc[tm][tn] = __builtin_amdgcn_mfma_f32_16x16x32_f16(af[tm], bf[tn], acc[tm][tn], 0, 0, 0);
    __syncthreads();
  }

  // ---- epilogue: bias, fp16 store, column stats ----
  float bsv[4];
#pragma unroll
  for (int tn = 0; tn < 4; ++tn) bsv[tn] = bias[n0 + wn * 64 + tn * 16 + (lane & 15)];
  float sacc[4] = {0.f, 0.f, 0.f, 0.f}, qacc[4] = {0.f, 0.f, 0.f, 0.f};
#pragma unroll
  for (int tm = 0; tm < 4; ++tm) {
    int nbase = m0 + wm * 64 + tm * 16 + (lane >> 4) * 4;
#pragma unroll
    for (int r = 0; r < 4; ++r) {
      int n = nbase + r;
      if (n < N_NODES) {
#pragma unroll
        for (int tn = 0; tn < 4; ++tn) {
          float v = acc[tm][tn][r] + bsv[tn];
          y1h[(size_t)n * 256 + n0 + wn * 64 + tn * 16 + (lane & 15)] = (_Float16)v;
          sacc[tn] += v; qacc[tn] += v * v;
        }
      }
    }
  }
#pragma unroll
  for (int tn = 0; tn < 4; ++tn) {
    int c = wn * 64 + tn * 16 + (lane & 15);
    atomicAdd(&ssum[c], sacc[tn]);
    atomicAdd(&ssq[c], qacc[tn]);
  }
  __syncthreads();
  if (tid < 128) {
    unsafeAtomicAdd(&gsum[n0 + tid], ssum[tid]);
    unsafeAtomicAdd(&gsq[n0 + tid], ssq[tid]);
  }
}

// ---------- GEMM2 (MFMA fp16): y2 = relu(bn1(y1h)) @ W2 + b2 ; col stats ----------
// block 256 thr = 4 waves (2x2), tile BM=64 x BN=128, K=256 in 8 steps of 32
__global__ __launch_bounds__(256) void k_gemm2m(const _Float16* __restrict__ y1h,
                                                const float* __restrict__ sc,
                                                const float* __restrict__ sh,
                                                const _Float16* __restrict__ w2t, // [128][256]
                                                const float* __restrict__ bias,   // [128]
                                                float* __restrict__ y2,
                                                float* __restrict__ gsum,
                                                float* __restrict__ gsq) {
  __shared__ _Float16 sA[64 * 40];
  __shared__ _Float16 sBT[128 * 40];
  __shared__ float ssc[256], ssh[256];
  __shared__ float ssum[128], ssq[128];
  const int tid = threadIdx.x;
  const int lane = tid & 63;
  const int wid = tid >> 6;
  const int wm = wid >> 1, wn = wid & 1;
  const int m0 = blockIdx.x * 64;

  ssc[tid] = sc[tid];
  ssh[tid] = sh[tid];
  if (tid < 128) { ssum[tid] = 0.f; ssq[tid] = 0.f; }
  __syncthreads();

  f32x4 acc[2][4];
  const f32x4 zz = {0.f, 0.f, 0.f, 0.f};
#pragma unroll
  for (int a = 0; a < 2; ++a)
#pragma unroll
    for (int b = 0; b < 4; ++b) acc[a][b] = zz;

  const int arow = tid >> 2;            // 0..63
  const int akq = (tid & 3) * 8;        // 0,8,16,24
  const int brow = tid >> 1;            // 0..127
  const int bkh = (tid & 1) * 16;       // 0,16

  for (int k0 = 0; k0 < 256; k0 += 32) {
    // ---- stage A: relu(y1h*sc+sh) -> fp16 ----
    {
      int n = m0 + arow;
      half8 p;
      if (n < N_NODES) {
        half8 yv = *(const half8*)&y1h[(size_t)n * 256 + k0 + akq];
#pragma unroll
        for (int j = 0; j < 8; ++j) {
          float v = fmaxf((float)yv[j] * ssc[k0 + akq + j] + ssh[k0 + akq + j], 0.f);
          p[j] = (_Float16)v;
        }
      } else {
#pragma unroll
        for (int j = 0; j < 8; ++j) p[j] = (_Float16)0.f;
      }
      *(half8*)&sA[arow * 40 + akq] = p;
    }
    // ---- stage B^T ----
    {
      half8 u0 = *(const half8*)&w2t[(size_t)brow * 256 + k0 + bkh];
      half8 u1 = *(const half8*)&w2t[(size_t)brow * 256 + k0 + bkh + 8];
      *(half8*)&sBT[brow * 40 + bkh] = u0;
      *(half8*)&sBT[brow * 40 + bkh + 8] = u1;
    }
    __syncthreads();
    half8 af[2], bf[4];
#pragma unroll
    for (int t = 0; t < 2; ++t)
      af[t] = *(const half8*)&sA[(wm * 32 + t * 16 + (lane & 15)) * 40 + (lane >> 4) * 8];
#pragma unroll
    for (int t = 0; t < 4; ++t)
      bf[t] = *(const half8*)&sBT[(wn * 64 + t * 16 + (lane & 15)) * 40 + (lane >> 4) * 8];
#pragma unroll
    for (int tm = 0; tm < 2; ++tm)
#pragma unroll
      for (int tn = 0; tn < 4; ++tn)
        acc[tm][tn] = __builtin_amdgcn_mfma_f32_16x16x32_f16(af[tm], bf[tn], acc[tm][tn], 0, 0, 0);
    __syncthreads();
  }

  // ---- epilogue ----
  float bsv[4];
#pragma unroll
  for (int tn = 0; tn < 4; ++tn) bsv[tn] = bias[wn * 64 + tn * 16 + (lane & 15)];
  float sacc[4] = {0.f, 0.f, 0.f, 0.f}, qacc[4] = {0.f, 0.f, 0.f, 0.f};
#pragma unroll
  for (int tm = 0; tm < 2; ++tm) {
    int nbase = m0 + wm * 32 + tm * 16 + (lane >> 4) * 4;
#pragma unroll
    for (int r = 0; r < 4; ++r) {
      int n = nbase + r;
      if (n < N_NODES) {
#pragma unroll
        for (int tn = 0; tn < 4; ++tn) {
          float v = acc[tm][tn][r] + bsv[tn];
          y2[(size_t)n * 128 + wn * 64 + tn * 16 + (lane & 15)] = v;
          sacc[tn] += v; qacc[tn] += v * v;
        }
      }
    }
  }
#pragma unroll
  for (int tn = 0; tn < 4; ++tn) {
    int c = wn * 64 + tn * 16 + (lane & 15);
    atomicAdd(&ssum[c], sacc[tn]);
    atomicAdd(&ssq[c], qacc[tn]);
  }
  __syncthreads();
  if (tid < 128) {
    unsafeAtomicAdd(&gsum[tid], ssum[tid]);
    unsafeAtomicAdd(&gsq[tid], ssq[tid]);
  }
}

// ---------------- BN finalize ----------------
__global__ void k_bnfin(const float* __restrict__ sum, const float* __restrict__ sq,
                        const float* __restrict__ g, const float* __restrict__ b,
                        float* __restrict__ sc, float* __restrict__ sh, int C) {
  int c = blockIdx.x * blockDim.x + threadIdx.x;
  if (c < C) {
    const float invN = 1.0f / (float)N_NODES;
    float m = sum[c] * invN;
    float v = fmaxf(sq[c] * invN - m * m, 0.0f);
    float rs = rsqrtf(v + 1e-5f);
    float scale = g[c] * rs;
    sc[c] = scale;
    sh[c] = b[c] - m * scale;
  }
}

// ---------------- apply BN (+optional relu) ----------------
__global__ __launch_bounds__(256) void k_bnapply(const float* __restrict__ y2,
                                                 const float* __restrict__ sc,
                                                 const float* __restrict__ sh,
                                                 float* __restrict__ h, int dorelu) {
  int i = blockIdx.x * 256 + threadIdx.x;
  if (i < N_NODES * 32) {
    int cv = i & 31;
    float4 v = *(const float4*)&y2[i * 4];
    float4 s4 = *(const float4*)&sc[cv * 4];
    float4 h4 = *(const float4*)&sh[cv * 4];
    float4 o;
    o.x = v.x * s4.x + h4.x; o.y = v.y * s4.y + h4.y;
    o.z = v.z * s4.z + h4.z; o.w = v.w * s4.w + h4.w;
    if (dorelu) {
      o.x = fmaxf(o.x, 0.f); o.y = fmaxf(o.y, 0.f);
      o.z = fmaxf(o.z, 0.f); o.w = fmaxf(o.w, 0.f);
    }
    *(float4*)&h[i * 4] = o;
  }
}

// ---------------- pooling: sorted-batch segment reduction ----------------
__global__ void k_goff(const int* __restrict__ batch, int* __restrict__ goff) {
  int g = blockIdx.x * blockDim.x + threadIdx.x;
  if (g <= NG) {
    if (g == NG) { goff[g] = N_NODES; return; }
    int lo = 0, hi = N_NODES;
    while (lo < hi) { int mid = (lo + hi) >> 1; if (batch[mid] < g) lo = mid + 1; else hi = mid; }
    goff[g] = lo;
  }
}

__global__ __launch_bounds__(256) void k_poolseg(const float* __restrict__ h,
                                                 const int* __restrict__ goff,
                                                 float* __restrict__ pooled) {
  __shared__ float sred[256];
  int g = blockIdx.x;
  int c = threadIdx.x & 127;
  int half = threadIdx.x >> 7;
  int n0 = goff[g], n1 = goff[g + 1];
  float s = 0.f;
  for (int n = n0 + half; n < n1; n += 2) s += h[(size_t)n * HD + c];
  sred[threadIdx.x] = s;
  __syncthreads();
  if (threadIdx.x < 128) {
    float tot = sred[threadIdx.x] + sred[threadIdx.x + 128];
    float cntf = (float)(n1 - n0);
    pooled[g * HD + threadIdx.x] = tot / fmaxf(cntf, 1.0f);
  }
}

// ---------------- final GEMM ----------------
__global__ __launch_bounds__(128) void k_final(const float* __restrict__ pooled,
                                               const float* __restrict__ oW,
                                               const float* __restrict__ ob,
                                               float* __restrict__ out) {
  __shared__ float sP[HD];
  int g = blockIdx.x;
  int c = threadIdx.x;
  sP[c] = pooled[g * HD + c];
  __syncthreads();
  float acc = ob[c];
#pragma unroll 8
  for (int k = 0; k < HD; ++k) acc += sP[k] * oW[k * HD + c];
  out[g * HD + c] = acc;
}

extern "C" void kernel_launch(void* const* d_in, const int* in_sizes, int n_in,
                              void* d_out, int out_size, void* d_ws, size_t ws_size,
                              hipStream_t stream) {
  const int* x = (const int*)d_in[0];
  const int* ei = (const int*)d_in[1];
  const float* ea = (const float*)d_in[2];
  const int* batch = (const int*)d_in[3];
  const float* emb = (const float*)d_in[4];
  const float* eW = (const float*)d_in[5];
  const float* eb = (const float*)d_in[6];
  const float* epsA = (const float*)d_in[7];
  const float* W1 = (const float*)d_in[8];
  const float* b1 = (const float*)d_in[9];
  const float* g1 = (const float*)d_in[10];
  const float* be1 = (const float*)d_in[11];
  const float* W2 = (const float*)d_in[12];
  const float* b2 = (const float*)d_in[13];
  const float* bng = (const float*)d_in[14];
  const float* bnb = (const float*)d_in[15];
  const float* oW = (const float*)d_in[16];
  const float* ob = (const float*)d_in[17];
  float* out = (float*)d_out;

  // ----- workspace layout: ints first, then floats -----
  int* ip = (int*)d_ws;
  int* deg = ip;                         // 50,000
  int* incl = deg + 50000;               // 50,000
  int* offs = incl + 50000;              // 50,001
  int* cursor = offs + 50001;            // 50,000
  int* srcs = cursor + 50000;            // 800,000
  int* eids = srcs + 800000;             // 800,000
  int* bsum = eids + 800000;             // 200
  int* goff = bsum + 200;                // 513
  float* fp = (float*)(ip + 1800916);
  float* h = fp;                         // 6,400,000
  float* zbuf = h + 6400000;             // 6,400,000 (z and y2 alias)
  _Float16* y1h = (_Float16*)(zbuf + 6400000);  // 12,800,000 halves = 6,400,000 floats
  float* stats = zbuf + 12800000;        // 768
  float* sc1 = stats + 768;              // 256
  float* sh1 = sc1 + 256;                // 256
  float* sc2 = sh1 + 256;                // 128
  float* sh2 = sc2 + 128;                // 128
  float* pooled = sh2 + 128;             // 65,536
  _Float16* w1t = (_Float16*)(pooled + 65536);  // 163,840 halves
  _Float16* w2t = w1t + 163840;                 // 163,840 halves
  float* ea_s = pooled + 65536 + 163840;        // 12,800,000 (optional)

  size_t needed_with = (size_t)(ea_s + 12800000 - (float*)d_ws) * 4;
  int permuted = (ws_size >= needed_with) ? 1 : 0;

  const int vec_blocks = (N_NODES * 32 + 255) / 256;
  const int edge_blocks = (N_EDGES + 255) / 256;
  const int node_blocks = (N_NODES + 255) / 256;

  k_embed<<<vec_blocks, 256, 0, stream>>>(x, emb, h);

  // CSR build + weight conversion (once per launch)
  hipMemsetAsync(deg, 0, 50000 * sizeof(int), stream);
  k_hist<<<edge_blocks, 256, 0, stream>>>(ei, deg);
  k_scan1<<<node_blocks, 256, 0, stream>>>(deg, incl, bsum);
  k_scan2<<<1, 256, 0, stream>>>(bsum, node_blocks);
  k_scan3<<<node_blocks, 256, 0, stream>>>(deg, incl, bsum, offs, cursor);
  k_scatter<<<edge_blocks, 256, 0, stream>>>(ei, ea, cursor, srcs, eids, ea_s, permuted);
  k_goff<<<3, 256, 0, stream>>>(batch, goff);
  k_cvtw1<<<640, 256, 0, stream>>>(W1, w1t);
  k_cvtw2<<<640, 256, 0, stream>>>(W2, w2t);

  for (int l = 0; l < NLAYERS; ++l) {
    hipMemsetAsync(stats, 0, 768 * sizeof(float), stream);
    k_aggr<<<(N_NODES + 3) / 4, 256, 0, stream>>>(offs, srcs, eids, ea, ea_s,
                                                  eW + (size_t)l * EINC * HD, eb + l * HD,
                                                  epsA, l, h, zbuf, permuted);
    k_gemm1m<<<dim3(391, 2), 256, 0, stream>>>(zbuf, w1t + (size_t)l * 32768,
                                               b1 + l * 256, y1h, stats, stats + 256);
    k_bnfin<<<1, 256, 0, stream>>>(stats, stats + 256, g1 + l * 256, be1 + l * 256, sc1, sh1, 256);
    k_gemm2m<<<782, 256, 0, stream>>>(y1h, sc1, sh1, w2t + (size_t)l * 32768,
                                      b2 + l * HD, zbuf, stats + 512, stats + 640);
    k_bnfin<<<1, 128, 0, stream>>>(stats + 512, stats + 640, bng + l * HD, bnb + l * HD, sc2, sh2, 128);
    k_bnapply<<<vec_blocks, 256, 0, stream>>>(zbuf, sc2, sh2, h, (l < NLAYERS - 1) ? 1 : 0);
  }

  k_poolseg<<<NG, 256, 0, stream>>>(h, goff, pooled);
  k_final<<<NG, 128, 0, stream>>>(pooled, oW, ob, out);
}